// Round 13
// baseline (328.970 us; speedup 1.0000x reference)
//
#include <hip/hip_runtime.h>
#include <hip/hip_bf16.h>

// GCN. CSR via 2-pass LDS bucket sort (wave-contiguous global writes only).
// Linearity exploited twice: layer1 gathers the 4 MB x-table then applies W1
// in-block; layer2 gathers h1 and applies W2 in-block (agg(hW)=agg(h)W) --
// no g/h2/aggx tables ever hit HBM. Natural node order (R12 showed perm
// sorting is neutral on the gather plateau and hurts csr locality).
// Features bf16, fp32 accumulate.

#define N_NODES 131072
#define N_EDGES 2097152
#define N_GRAPHS 2048
#define IN_CH 12
#define HID 64
#define OUT_CH 4
#define NBUCK 512          // buckets of 256 dst nodes
#define CHUNK 8192         // edges per bucket_kernel block
#define STRIDE 4608        // staging capacity per bucket
#define CSR_STRIDE 5120    // csr capacity per bucket (padded x4)
#define CAP 5120           // place_kernel LDS image capacity (40 KB)
#define SH_PITCH 68        // 32-row LDS pitch: 68%32=4 -> distinct banks, 16B-aligned
#define SA_PITCH 20        // 128-row LDS pitch: banks nl*20%32 distinct, 16B-aligned

typedef float f32x2 __attribute__((ext_vector_type(2)));

__device__ __forceinline__ unsigned short f2bf(float f) {
    unsigned u = __float_as_uint(f);
    return (unsigned short)((u + 0x7fffu + ((u >> 16) & 1u)) >> 16);  // RNE
}
__device__ __forceinline__ unsigned pack2bf(float lo, float hi) {
    return (unsigned)f2bf(lo) | ((unsigned)f2bf(hi) << 16);
}
__device__ __forceinline__ float bflo(unsigned v) { return __uint_as_float(v << 16); }
__device__ __forceinline__ float bfhi(unsigned v) { return __uint_as_float(v & 0xFFFF0000u); }

// ---- pass A: LDS bucket sort of edges by dst>>8 into strided staging ----
__global__ __launch_bounds__(1024, 4)
void bucket_kernel(const int* __restrict__ src, const int* __restrict__ dst,
                   int* __restrict__ bucket_count, int* __restrict__ staged) {
    __shared__ int hist[NBUCK];
    __shared__ int lscan[NBUCK];
    __shared__ int gbase[NBUCK];
    __shared__ int cursor[NBUCK];
    __shared__ int sorted[CHUNK];  // 32 KB
    int tid = threadIdx.x;
    int base = blockIdx.x * CHUNK;
    if (tid < NBUCK) { hist[tid] = 0; cursor[tid] = 0; }
    __syncthreads();
    int d8[8], s8[8];
#pragma unroll
    for (int k = 0; k < 8; k++) {
        int i = base + k * 1024 + tid;
        d8[k] = dst[i];
        s8[k] = src[i];
        atomicAdd(&hist[d8[k] >> 8], 1);
    }
    __syncthreads();
    if (tid < NBUCK) lscan[tid] = hist[tid];
    __syncthreads();
    for (int off = 1; off < NBUCK; off <<= 1) {
        int u = (tid < NBUCK && tid >= off) ? lscan[tid - off] : 0;
        __syncthreads();
        if (tid < NBUCK) lscan[tid] += u;
        __syncthreads();
    }
    if (tid < NBUCK) gbase[tid] = atomicAdd(&bucket_count[tid], hist[tid]);
    __syncthreads();
#pragma unroll
    for (int k = 0; k < 8; k++) {
        int b = d8[k] >> 8;
        int start = lscan[b] - hist[b];
        int p = start + atomicAdd(&cursor[b], 1);
        sorted[p] = ((d8[k] & 255) << 17) | s8[k];
    }
    __syncthreads();
    int wid = tid >> 6, lane = tid & 63;
    int g16 = lane >> 4, k16 = lane & 15;
    for (int b0 = wid * 4; b0 < NBUCK; b0 += 64) {
        int b = b0 + g16;
        int cb = hist[b];
        int lbase = lscan[b] - cb;
        int gb = b * STRIDE + gbase[b];
        for (int k = k16; k < cb; k += 16) staged[gb + k] = sorted[lbase + k];
    }
}

// ---- per-bucket: fine degree count in LDS -> padded rowbounds, dinv ----
__global__ void count_kernel(const int* __restrict__ bucket_count, const int* __restrict__ staged,
                             int2* __restrict__ rowbounds, float* __restrict__ dinv) {
    __shared__ int cnt[256];
    __shared__ int scn[256];
    int b = blockIdx.x;
    int tid = threadIdx.x;
    int count = bucket_count[b];
    const int* st = staged + b * STRIDE;
    cnt[tid] = 0;
    __syncthreads();
    for (int i = tid; i < count; i += 256) atomicAdd(&cnt[(st[i] >> 17) & 255], 1);
    __syncthreads();
    int deg = cnt[tid];
    int degp = (deg + 3) & ~3;  // pad to x4
    scn[tid] = degp;
    __syncthreads();
    for (int off = 1; off < 256; off <<= 1) {
        int u = (tid >= off) ? scn[tid - off] : 0;
        __syncthreads();
        scn[tid] += u;
        __syncthreads();
    }
    int nbase = (b << 8) + tid;
    int gbeg = b * CSR_STRIDE + scn[tid] - degp;
    rowbounds[nbase] = make_int2(gbeg, gbeg + degp);
    dinv[nbase] = rsqrtf((float)deg + 1.0f);
}

// ---- per-bucket: place records (+zero pads) into CSR via LDS image ----
__global__ void place_kernel(const int* __restrict__ bucket_count, const int* __restrict__ staged,
                             const int2* __restrict__ rowbounds, const float* __restrict__ dinv,
                             int2* __restrict__ csr) {
    __shared__ int loff[256];
    __shared__ int cursor[256];
    __shared__ float ldinv[256];
    __shared__ int totalS;
    __shared__ int2 image[CAP];  // 40 KB
    int b = blockIdx.x;
    int tid = threadIdx.x;
    int nbase = (b << 8) + tid;
    int gb = b * CSR_STRIDE;
    int count = bucket_count[b];
    int2 rb = rowbounds[nbase];
    int lo = rb.x - gb;
    int degp = rb.y - rb.x;
    loff[tid] = lo;
    cursor[tid] = 0;
    ldinv[tid] = dinv[nbase];
    if (tid == 255) totalS = lo + degp;
    __syncthreads();
    const int* st = staged + b * STRIDE;
    for (int i = tid; i < count; i += 256) {
        int rec = st[i];
        int s = rec & 0x1FFFF;
        int dq = (rec >> 17) & 255;
        float norm = dinv[s] * ldinv[dq];
        int p = loff[dq] + atomicAdd(&cursor[dq], 1);
        int2 val = make_int2(s << 6, __float_as_int(norm));  // pre-scaled src offset (x64)
        if (p < CAP) image[p] = val;
        else csr[gb + p] = val;
    }
    __syncthreads();
    for (int p = lo + cursor[tid]; p < lo + degp; p++) {
        int2 z = make_int2(0, 0);
        if (p < CAP) image[p] = z;
        else csr[gb + p] = z;
    }
    __syncthreads();
    int lim = totalS < CAP ? totalS : CAP;
    int2* dstp = csr + gb;
    for (int i = tid; i < lim; i += 256) dstp[i] = image[i];
}

// ---- x fp32[N,12] -> bf16[N,16] zero-padded ----
__global__ void xcast_kernel(const float* __restrict__ x, unsigned short* __restrict__ xb) {
    int n = blockIdx.x * 256 + threadIdx.x;
    const float* xp = x + n * IN_CH;
    unsigned o[8];
#pragma unroll
    for (int k = 0; k < 6; k++) o[k] = pack2bf(xp[2 * k], xp[2 * k + 1]);
    o[6] = 0; o[7] = 0;
    uint4* dst = (uint4*)(xb + n * 16);
    dst[0] = make_uint4(o[0], o[1], o[2], o[3]);
    dst[1] = make_uint4(o[4], o[5], o[6], o[7]);
}

// ---- fused layer 1: agg(x) in-block, then @W1 + b1 + relu -> h1 bf16 ----
// 128 nodes/block (4 waves x 32 nodes; 2-lane subgroups over 16 channels).
__global__ void agg_x_w1_kernel(const int2* __restrict__ rowbounds, const int2* __restrict__ csr,
                                const float* __restrict__ dinv,
                                const unsigned short* __restrict__ xb,
                                const float* __restrict__ W1, const float* __restrict__ b1,
                                unsigned short* __restrict__ h1) {
    __shared__ float sA[128 * SA_PITCH];   // 10 KB aggregated x rows
    __shared__ float sW[IN_CH * HID];      // 3 KB
    int tid = threadIdx.x;
    for (int i = tid; i < IN_CH * HID; i += 256) sW[i] = W1[i];
    int w = tid >> 6, lane = tid & 63, sub = lane >> 1, p = lane & 1;
    int qoff = 8 * p;
    int nl = w * 32 + sub;
    int node = blockIdx.x * 128 + nl;
    int2 rb = rowbounds[node];
    float dn = dinv[node];
    f32x2 a0[4] = {{0, 0}, {0, 0}, {0, 0}, {0, 0}};
    f32x2 a1[4] = {{0, 0}, {0, 0}, {0, 0}, {0, 0}};
    f32x2 a2[4] = {{0, 0}, {0, 0}, {0, 0}, {0, 0}};
    f32x2 a3[4] = {{0, 0}, {0, 0}, {0, 0}, {0, 0}};
    for (int j = rb.x; j < rb.y; j += 4) {  // padded x4: no remainder
        int4 e01 = *(const int4*)(csr + j);
        int4 e23 = *(const int4*)(csr + j + 2);
        uint4 u0 = *(const uint4*)(xb + (e01.x >> 2) + qoff);  // src<<6 -> x16 row
        uint4 u1 = *(const uint4*)(xb + (e01.z >> 2) + qoff);
        uint4 u2 = *(const uint4*)(xb + (e23.x >> 2) + qoff);
        uint4 u3 = *(const uint4*)(xb + (e23.z >> 2) + qoff);
        float n0 = __int_as_float(e01.y), n1 = __int_as_float(e01.w);
        float n2 = __int_as_float(e23.y), n3 = __int_as_float(e23.w);
        f32x2 nn0 = {n0, n0}, nn1 = {n1, n1}, nn2 = {n2, n2}, nn3 = {n3, n3};
        a0[0] += nn0 * (f32x2){bflo(u0.x), bfhi(u0.x)};
        a0[1] += nn0 * (f32x2){bflo(u0.y), bfhi(u0.y)};
        a0[2] += nn0 * (f32x2){bflo(u0.z), bfhi(u0.z)};
        a0[3] += nn0 * (f32x2){bflo(u0.w), bfhi(u0.w)};
        a1[0] += nn1 * (f32x2){bflo(u1.x), bfhi(u1.x)};
        a1[1] += nn1 * (f32x2){bflo(u1.y), bfhi(u1.y)};
        a1[2] += nn1 * (f32x2){bflo(u1.z), bfhi(u1.z)};
        a1[3] += nn1 * (f32x2){bflo(u1.w), bfhi(u1.w)};
        a2[0] += nn2 * (f32x2){bflo(u2.x), bfhi(u2.x)};
        a2[1] += nn2 * (f32x2){bflo(u2.y), bfhi(u2.y)};
        a2[2] += nn2 * (f32x2){bflo(u2.z), bfhi(u2.z)};
        a2[3] += nn2 * (f32x2){bflo(u2.w), bfhi(u2.w)};
        a3[0] += nn3 * (f32x2){bflo(u3.x), bfhi(u3.x)};
        a3[1] += nn3 * (f32x2){bflo(u3.y), bfhi(u3.y)};
        a3[2] += nn3 * (f32x2){bflo(u3.z), bfhi(u3.z)};
        a3[3] += nn3 * (f32x2){bflo(u3.w), bfhi(u3.w)};
    }
    uint4 su = *(const uint4*)(xb + node * 16 + qoff);
    float dn2 = dn * dn;
    f32x2 nd = {dn2, dn2};
    a0[0] += nd * (f32x2){bflo(su.x), bfhi(su.x)};
    a0[1] += nd * (f32x2){bflo(su.y), bfhi(su.y)};
    a0[2] += nd * (f32x2){bflo(su.z), bfhi(su.z)};
    a0[3] += nd * (f32x2){bflo(su.w), bfhi(su.w)};
    f32x2 s0 = (a0[0] + a1[0]) + (a2[0] + a3[0]);
    f32x2 s1 = (a0[1] + a1[1]) + (a2[1] + a3[1]);
    f32x2 s2 = (a0[2] + a1[2]) + (a2[2] + a3[2]);
    f32x2 s3 = (a0[3] + a1[3]) + (a2[3] + a3[3]);
    float4 o0 = make_float4(s0[0], s0[1], s1[0], s1[1]);
    float4 o1 = make_float4(s2[0], s2[1], s3[0], s3[1]);
    *(float4*)&sA[nl * SA_PITCH + qoff] = o0;
    *(float4*)&sA[nl * SA_PITCH + qoff + 4] = o1;
    __syncthreads();
    // phase 2: h1[n] = relu(sA[n,:12] @ W1 + b1), 8 ch/thread, 4 node-iters
    int c8 = (tid & 7) * 8;
    float4 bb0 = *(const float4*)&b1[c8];
    float4 bb1 = *(const float4*)&b1[c8 + 4];
#pragma unroll
    for (int it = 0; it < 4; it++) {
        int n2l = it * 32 + (tid >> 3);
        float acc[8] = {bb0.x, bb0.y, bb0.z, bb0.w, bb1.x, bb1.y, bb1.z, bb1.w};
#pragma unroll
        for (int k = 0; k < IN_CH; k++) {
            float av = sA[n2l * SA_PITCH + k];
            float4 w0 = *(const float4*)&sW[k * HID + c8];
            float4 w1v = *(const float4*)&sW[k * HID + c8 + 4];
            acc[0] += av * w0.x; acc[1] += av * w0.y; acc[2] += av * w0.z; acc[3] += av * w0.w;
            acc[4] += av * w1v.x; acc[5] += av * w1v.y; acc[6] += av * w1v.z; acc[7] += av * w1v.w;
        }
        uint4 o;
        o.x = pack2bf(fmaxf(acc[0], 0.0f), fmaxf(acc[1], 0.0f));
        o.y = pack2bf(fmaxf(acc[2], 0.0f), fmaxf(acc[3], 0.0f));
        o.z = pack2bf(fmaxf(acc[4], 0.0f), fmaxf(acc[5], 0.0f));
        o.w = pack2bf(fmaxf(acc[6], 0.0f), fmaxf(acc[7], 0.0f));
        *(uint4*)(h1 + (blockIdx.x * 128 + n2l) * HID + c8) = o;
    }
}

// ---- fused layer 2 + pool: agg(h1) in-block, @W2 + b2 + relu, run-length pool ----
// 32 nodes/block (4 waves x 8 nodes; 8-lane subgroups over 64 channels).
__global__ void agg_w2_pool_kernel(const int2* __restrict__ rowbounds,
                                   const int2* __restrict__ csr,
                                   const float* __restrict__ dinv,
                                   const unsigned short* __restrict__ h,
                                   const float* __restrict__ W2, const float* __restrict__ b2,
                                   const int* __restrict__ batch,
                                   float* __restrict__ pool, float* __restrict__ gcnt) {
    __shared__ float sh[32 * SH_PITCH];  // 8.7 KB agg rows, then h2 rows
    __shared__ float sW[HID * HID];      // 16 KB
    __shared__ int gids[32];
    int tid = threadIdx.x;
    for (int i = tid; i < HID * HID; i += 256) sW[i] = W2[i];
    int w = tid >> 6, lane = tid & 63, sub = lane >> 3, q = lane & 7;
    int qoff = 8 * q;
    int nl = w * 8 + sub;
    int node = blockIdx.x * 32 + nl;
    int2 rb = rowbounds[node];
    float dn = dinv[node];
    f32x2 a0[4] = {{0, 0}, {0, 0}, {0, 0}, {0, 0}};
    f32x2 a1[4] = {{0, 0}, {0, 0}, {0, 0}, {0, 0}};
    f32x2 a2[4] = {{0, 0}, {0, 0}, {0, 0}, {0, 0}};
    f32x2 a3[4] = {{0, 0}, {0, 0}, {0, 0}, {0, 0}};
    for (int j = rb.x; j < rb.y; j += 4) {  // padded x4: no remainder
        int4 e01 = *(const int4*)(csr + j);
        int4 e23 = *(const int4*)(csr + j + 2);
        uint4 u0 = *(const uint4*)(h + e01.x + qoff);
        uint4 u1 = *(const uint4*)(h + e01.z + qoff);
        uint4 u2 = *(const uint4*)(h + e23.x + qoff);
        uint4 u3 = *(const uint4*)(h + e23.z + qoff);
        float n0 = __int_as_float(e01.y), n1 = __int_as_float(e01.w);
        float n2 = __int_as_float(e23.y), n3 = __int_as_float(e23.w);
        f32x2 nn0 = {n0, n0}, nn1 = {n1, n1}, nn2 = {n2, n2}, nn3 = {n3, n3};
        a0[0] += nn0 * (f32x2){bflo(u0.x), bfhi(u0.x)};
        a0[1] += nn0 * (f32x2){bflo(u0.y), bfhi(u0.y)};
        a0[2] += nn0 * (f32x2){bflo(u0.z), bfhi(u0.z)};
        a0[3] += nn0 * (f32x2){bflo(u0.w), bfhi(u0.w)};
        a1[0] += nn1 * (f32x2){bflo(u1.x), bfhi(u1.x)};
        a1[1] += nn1 * (f32x2){bflo(u1.y), bfhi(u1.y)};
        a1[2] += nn1 * (f32x2){bflo(u1.z), bfhi(u1.z)};
        a1[3] += nn1 * (f32x2){bflo(u1.w), bfhi(u1.w)};
        a2[0] += nn2 * (f32x2){bflo(u2.x), bfhi(u2.x)};
        a2[1] += nn2 * (f32x2){bflo(u2.y), bfhi(u2.y)};
        a2[2] += nn2 * (f32x2){bflo(u2.z), bfhi(u2.z)};
        a2[3] += nn2 * (f32x2){bflo(u2.w), bfhi(u2.w)};
        a3[0] += nn3 * (f32x2){bflo(u3.x), bfhi(u3.x)};
        a3[1] += nn3 * (f32x2){bflo(u3.y), bfhi(u3.y)};
        a3[2] += nn3 * (f32x2){bflo(u3.z), bfhi(u3.z)};
        a3[3] += nn3 * (f32x2){bflo(u3.w), bfhi(u3.w)};
    }
    uint4 su = *(const uint4*)(h + node * HID + qoff);
    float dn2 = dn * dn;
    f32x2 nd = {dn2, dn2};
    a0[0] += nd * (f32x2){bflo(su.x), bfhi(su.x)};
    a0[1] += nd * (f32x2){bflo(su.y), bfhi(su.y)};
    a0[2] += nd * (f32x2){bflo(su.z), bfhi(su.z)};
    a0[3] += nd * (f32x2){bflo(su.w), bfhi(su.w)};
    f32x2 s0 = (a0[0] + a1[0]) + (a2[0] + a3[0]);
    f32x2 s1 = (a0[1] + a1[1]) + (a2[1] + a3[1]);
    f32x2 s2 = (a0[2] + a1[2]) + (a2[2] + a3[2]);
    f32x2 s3 = (a0[3] + a1[3]) + (a2[3] + a3[3]);
    *(float4*)&sh[nl * SH_PITCH + qoff] = make_float4(s0[0], s0[1], s1[0], s1[1]);
    *(float4*)&sh[nl * SH_PITCH + qoff + 4] = make_float4(s2[0], s2[1], s3[0], s3[1]);
    if (q == 0) gids[nl] = batch[node];
    __syncthreads();
    // phase 2: h2[n] = relu(sh[n,:] @ W2 + b2); 8 ch/thread
    int n2l = tid >> 3, c8 = (tid & 7) * 8;
    float4 bb0 = *(const float4*)&b2[c8];
    float4 bb1 = *(const float4*)&b2[c8 + 4];
    float acc[8] = {bb0.x, bb0.y, bb0.z, bb0.w, bb1.x, bb1.y, bb1.z, bb1.w};
#pragma unroll 8
    for (int k = 0; k < HID; k++) {
        float hv = sh[n2l * SH_PITCH + k];
        float4 w0 = *(const float4*)&sW[k * HID + c8];
        float4 w1v = *(const float4*)&sW[k * HID + c8 + 4];
        acc[0] += hv * w0.x; acc[1] += hv * w0.y; acc[2] += hv * w0.z; acc[3] += hv * w0.w;
        acc[4] += hv * w1v.x; acc[5] += hv * w1v.y; acc[6] += hv * w1v.z; acc[7] += hv * w1v.w;
    }
    __syncthreads();  // all reads of sh done before overwrite
    *(float4*)&sh[n2l * SH_PITCH + c8] =
        make_float4(fmaxf(acc[0], 0.0f), fmaxf(acc[1], 0.0f),
                    fmaxf(acc[2], 0.0f), fmaxf(acc[3], 0.0f));
    *(float4*)&sh[n2l * SH_PITCH + c8 + 4] =
        make_float4(fmaxf(acc[4], 0.0f), fmaxf(acc[5], 0.0f),
                    fmaxf(acc[6], 0.0f), fmaxf(acc[7], 0.0f));
    __syncthreads();
    if (tid < 64) {  // wave 0: run-length reduce 32 nodes (batch sorted)
        int c = tid;
        float acc2 = 0.0f;
        int cur = gids[0], cnt = 0;
        for (int n = 0; n < 32; n++) {
            int g = gids[n];
            if (g != cur) {
                atomicAdd(&pool[cur * HID + c], acc2);
                if (c == 0) atomicAdd(&gcnt[cur], (float)cnt);
                acc2 = 0.0f; cnt = 0; cur = g;
            }
            acc2 += sh[n * SH_PITCH + c];
            cnt++;
        }
        atomicAdd(&pool[cur * HID + c], acc2);
        if (c == 0) atomicAdd(&gcnt[cur], (float)cnt);
    }
}

// ---- final: out = sigmoid((pool/cnt) @ Wfc + bfc) ----
__global__ void final_kernel(const float* __restrict__ pool, const float* __restrict__ gcnt,
                             const float* __restrict__ Wfc, const float* __restrict__ bfc,
                             float* __restrict__ out) {
    int idx = blockIdx.x * 256 + threadIdx.x;
    if (idx >= N_GRAPHS * OUT_CH) return;
    int g = idx >> 2, o = idx & 3;
    float inv = 1.0f / fmaxf(gcnt[g], 1.0f);
    float acc = bfc[o];
#pragma unroll
    for (int k = 0; k < HID; k++) acc += pool[g * HID + k] * inv * Wfc[k * OUT_CH + o];
    out[idx] = 1.0f / (1.0f + expf(-acc));
}

extern "C" void kernel_launch(void* const* d_in, const int* in_sizes, int n_in,
                              void* d_out, int out_size, void* d_ws, size_t ws_size,
                              hipStream_t stream) {
    const float* x   = (const float*)d_in[0];
    const int* eidx  = (const int*)d_in[1];
    const int* batch = (const int*)d_in[2];
    const float* W1  = (const float*)d_in[3];
    const float* b1  = (const float*)d_in[4];
    const float* W2  = (const float*)d_in[5];
    const float* b2  = (const float*)d_in[6];
    const float* Wfc = (const float*)d_in[7];
    const float* bfc = (const float*)d_in[8];
    float* out = (float*)d_out;

    const int* src = eidx;
    const int* dst = eidx + N_EDGES;

    // workspace layout (~53 MB; ws is larger)
    unsigned short* hA = (unsigned short*)d_ws;              // 16 MB bf16 (h1 table)
    int2*  csr    = (int2*)(hA + (size_t)N_NODES * HID);     // 21 MB {src<<6, norm}
    int*   staged = (int*)(csr + (size_t)NBUCK * CSR_STRIDE); // 9.4 MB
    float* dinv   = (float*)(staged + (size_t)NBUCK * STRIDE); // 512 KB
    int2*  rowbounds = (int2*)(dinv + N_NODES);              // 1 MB
    int*   bucket_count = (int*)(rowbounds + N_NODES);       // 2 KB
    float* pool   = (float*)(bucket_count + NBUCK);          // 512 KB
    float* gcnt   = pool + N_GRAPHS * HID;                   // 8 KB
    unsigned short* xb = (unsigned short*)(gcnt + N_GRAPHS); // 4 MB bf16 [N,16]

    hipMemsetAsync(bucket_count, 0, (size_t)NBUCK * 4, stream);
    hipMemsetAsync(pool, 0, (size_t)(N_GRAPHS * HID + N_GRAPHS) * 4, stream);

    // CSR build
    bucket_kernel<<<N_EDGES / CHUNK, 1024, 0, stream>>>(src, dst, bucket_count, staged);
    count_kernel<<<NBUCK, 256, 0, stream>>>(bucket_count, staged, rowbounds, dinv);
    place_kernel<<<NBUCK, 256, 0, stream>>>(bucket_count, staged, rowbounds, dinv, csr);

    // layer 1 (fused agg + W1)
    xcast_kernel<<<N_NODES / 256, 256, 0, stream>>>(x, xb);
    agg_x_w1_kernel<<<N_NODES / 128, 256, 0, stream>>>(rowbounds, csr, dinv, xb, W1, b1, hA);

    // layer 2 + pool (fused agg + W2 + relu + mean-pool)
    agg_w2_pool_kernel<<<N_NODES / 32, 256, 0, stream>>>(rowbounds, csr, dinv, hA, W2, b2,
                                                         batch, pool, gcnt);

    // head
    final_kernel<<<(N_GRAPHS * OUT_CH + 255) / 256, 256, 0, stream>>>(pool, gcnt, Wfc, bfc, out);
}

// Round 14
// 232.156 us; speedup vs baseline: 1.4170x; 1.4170x over previous
//
#include <hip/hip_runtime.h>
#include <hip/hip_bf16.h>

// GCN. CSR via 2-pass LDS bucket sort (wave-contiguous global writes only).
// Layer 1 exploits agg(xW) = agg(x)W: gather the 16-ch-padded bf16 x table
// (4 MB, ~L2-resident/XCD) instead of the 64-ch h table (16 MB). Matmuls
// (w1, hw2) stay as SEPARATE streaming kernels — R13 showed fusing them into
// the gather causes scratch spill (205 MB spill traffic, 0.4% occupancy) or
// serialization (agg_w2_pool 106 us). Rows padded to x4. Layer-2 agg: wave =
// 8 nodes, lane = 8 ch, 8 gathers in flight per subgroup. bf16 feats, fp32 acc.

#define N_NODES 131072
#define N_EDGES 2097152
#define N_GRAPHS 2048
#define IN_CH 12
#define HID 64
#define OUT_CH 4
#define NBUCK 512          // buckets of 256 dst nodes
#define CHUNK 8192         // edges per bucket_kernel block
#define STRIDE 4608        // staging capacity per bucket (mean 4096, sd 64)
#define CSR_STRIDE 5120    // csr capacity per bucket (padded mean ~4500)
#define CAP 5120           // place_kernel LDS image capacity (40 KB)

typedef float f32x2 __attribute__((ext_vector_type(2)));

__device__ __forceinline__ unsigned short f2bf(float f) {
    unsigned u = __float_as_uint(f);
    return (unsigned short)((u + 0x7fffu + ((u >> 16) & 1u)) >> 16);  // RNE
}
__device__ __forceinline__ unsigned pack2bf(float lo, float hi) {
    return (unsigned)f2bf(lo) | ((unsigned)f2bf(hi) << 16);
}
__device__ __forceinline__ float bflo(unsigned v) { return __uint_as_float(v << 16); }
__device__ __forceinline__ float bfhi(unsigned v) { return __uint_as_float(v & 0xFFFF0000u); }

// ---- pass A: LDS bucket sort of edges by dst>>8 into strided staging ----
__global__ __launch_bounds__(1024, 4)
void bucket_kernel(const int* __restrict__ src, const int* __restrict__ dst,
                   int* __restrict__ bucket_count, int* __restrict__ staged) {
    __shared__ int hist[NBUCK];
    __shared__ int lscan[NBUCK];
    __shared__ int gbase[NBUCK];
    __shared__ int cursor[NBUCK];
    __shared__ int sorted[CHUNK];  // 32 KB
    int tid = threadIdx.x;
    int base = blockIdx.x * CHUNK;
    if (tid < NBUCK) { hist[tid] = 0; cursor[tid] = 0; }
    __syncthreads();
    int d8[8], s8[8];
#pragma unroll
    for (int k = 0; k < 8; k++) {
        int i = base + k * 1024 + tid;
        d8[k] = dst[i];
        s8[k] = src[i];
        atomicAdd(&hist[d8[k] >> 8], 1);
    }
    __syncthreads();
    if (tid < NBUCK) lscan[tid] = hist[tid];
    __syncthreads();
    for (int off = 1; off < NBUCK; off <<= 1) {
        int u = (tid < NBUCK && tid >= off) ? lscan[tid - off] : 0;
        __syncthreads();
        if (tid < NBUCK) lscan[tid] += u;
        __syncthreads();
    }
    if (tid < NBUCK) gbase[tid] = atomicAdd(&bucket_count[tid], hist[tid]);
    __syncthreads();
#pragma unroll
    for (int k = 0; k < 8; k++) {
        int b = d8[k] >> 8;
        int start = lscan[b] - hist[b];
        int p = start + atomicAdd(&cursor[b], 1);
        sorted[p] = ((d8[k] & 255) << 17) | s8[k];
    }
    __syncthreads();
    int wid = tid >> 6, lane = tid & 63;
    int g16 = lane >> 4, k16 = lane & 15;
    for (int b0 = wid * 4; b0 < NBUCK; b0 += 64) {
        int b = b0 + g16;
        int cb = hist[b];
        int lbase = lscan[b] - cb;
        int gb = b * STRIDE + gbase[b];
        for (int k = k16; k < cb; k += 16) staged[gb + k] = sorted[lbase + k];
    }
}

// ---- per-bucket: fine degree count in LDS -> padded rowbounds, dinv ----
__global__ void count_kernel(const int* __restrict__ bucket_count, const int* __restrict__ staged,
                             int2* __restrict__ rowbounds, float* __restrict__ dinv) {
    __shared__ int cnt[256];
    __shared__ int scn[256];
    int b = blockIdx.x;
    int tid = threadIdx.x;
    int count = bucket_count[b];
    const int* st = staged + b * STRIDE;
    cnt[tid] = 0;
    __syncthreads();
    for (int i = tid; i < count; i += 256) atomicAdd(&cnt[(st[i] >> 17) & 255], 1);
    __syncthreads();
    int deg = cnt[tid];
    int degp = (deg + 3) & ~3;  // pad to x4
    scn[tid] = degp;
    __syncthreads();
    for (int off = 1; off < 256; off <<= 1) {
        int u = (tid >= off) ? scn[tid - off] : 0;
        __syncthreads();
        scn[tid] += u;
        __syncthreads();
    }
    int nbase = (b << 8) + tid;
    int gbeg = b * CSR_STRIDE + scn[tid] - degp;
    rowbounds[nbase] = make_int2(gbeg, gbeg + degp);
    dinv[nbase] = rsqrtf((float)deg + 1.0f);
}

// ---- per-bucket: place records (+zero pads) into CSR via LDS image ----
__global__ void place_kernel(const int* __restrict__ bucket_count, const int* __restrict__ staged,
                             const int2* __restrict__ rowbounds, const float* __restrict__ dinv,
                             int2* __restrict__ csr) {
    __shared__ int loff[256];
    __shared__ int cursor[256];
    __shared__ float ldinv[256];
    __shared__ int totalS;
    __shared__ int2 image[CAP];  // 40 KB
    int b = blockIdx.x;
    int tid = threadIdx.x;
    int nbase = (b << 8) + tid;
    int gb = b * CSR_STRIDE;
    int count = bucket_count[b];
    int2 rb = rowbounds[nbase];
    int lo = rb.x - gb;
    int degp = rb.y - rb.x;
    loff[tid] = lo;
    cursor[tid] = 0;
    ldinv[tid] = dinv[nbase];
    if (tid == 255) totalS = lo + degp;
    __syncthreads();
    const int* st = staged + b * STRIDE;
    for (int i = tid; i < count; i += 256) {
        int rec = st[i];
        int s = rec & 0x1FFFF;
        int dq = (rec >> 17) & 255;
        float norm = dinv[s] * ldinv[dq];  // dinv 512 KB -> L2-resident
        int p = loff[dq] + atomicAdd(&cursor[dq], 1);
        int2 val = make_int2(s << 6, __float_as_int(norm));  // pre-scaled src offset (x64)
        if (p < CAP) image[p] = val;
        else csr[gb + p] = val;
    }
    __syncthreads();
    for (int p = lo + cursor[tid]; p < lo + degp; p++) {
        int2 z = make_int2(0, 0);
        if (p < CAP) image[p] = z;
        else csr[gb + p] = z;
    }
    __syncthreads();
    int lim = totalS < CAP ? totalS : CAP;
    int2* dstp = csr + gb;
    for (int i = tid; i < lim; i += 256) dstp[i] = image[i];
}

// ---- x fp32[N,12] -> bf16[N,16] zero-padded ----
__global__ void xcast_kernel(const float* __restrict__ x, unsigned short* __restrict__ xb) {
    int n = blockIdx.x * 256 + threadIdx.x;
    const float* xp = x + n * IN_CH;
    unsigned o[8];
#pragma unroll
    for (int k = 0; k < 6; k++) o[k] = pack2bf(xp[2 * k], xp[2 * k + 1]);
    o[6] = 0; o[7] = 0;
    uint4* dst = (uint4*)(xb + n * 16);
    dst[0] = make_uint4(o[0], o[1], o[2], o[3]);
    dst[1] = make_uint4(o[4], o[5], o[6], o[7]);
}

// ---- layer-1 aggregation over x table: wave = 32 nodes, 2-lane subgroups ----
__global__ void agg_x_kernel(const int2* __restrict__ rowbounds, const int2* __restrict__ csr,
                             const float* __restrict__ dinv,
                             const unsigned short* __restrict__ xb, float* __restrict__ aggx) {
    int tid = threadIdx.x;
    int w = tid >> 6, lane = tid & 63, sub = lane >> 1, p = lane & 1;
    int qoff = 8 * p;
    int node = (blockIdx.x * 4 + w) * 32 + sub;
    int2 rb = rowbounds[node];
    float dn = dinv[node];
    f32x2 a0[4] = {{0, 0}, {0, 0}, {0, 0}, {0, 0}};
    f32x2 a1[4] = {{0, 0}, {0, 0}, {0, 0}, {0, 0}};
    f32x2 a2[4] = {{0, 0}, {0, 0}, {0, 0}, {0, 0}};
    f32x2 a3[4] = {{0, 0}, {0, 0}, {0, 0}, {0, 0}};
    for (int j = rb.x; j < rb.y; j += 4) {  // padded x4: no remainder
        int4 e01 = *(const int4*)(csr + j);
        int4 e23 = *(const int4*)(csr + j + 2);
        uint4 u0 = *(const uint4*)(xb + (e01.x >> 2) + qoff);  // src<<6 -> x16 row
        uint4 u1 = *(const uint4*)(xb + (e01.z >> 2) + qoff);
        uint4 u2 = *(const uint4*)(xb + (e23.x >> 2) + qoff);
        uint4 u3 = *(const uint4*)(xb + (e23.z >> 2) + qoff);
        float n0 = __int_as_float(e01.y), n1 = __int_as_float(e01.w);
        float n2 = __int_as_float(e23.y), n3 = __int_as_float(e23.w);
        f32x2 nn0 = {n0, n0}, nn1 = {n1, n1}, nn2 = {n2, n2}, nn3 = {n3, n3};
        a0[0] += nn0 * (f32x2){bflo(u0.x), bfhi(u0.x)};
        a0[1] += nn0 * (f32x2){bflo(u0.y), bfhi(u0.y)};
        a0[2] += nn0 * (f32x2){bflo(u0.z), bfhi(u0.z)};
        a0[3] += nn0 * (f32x2){bflo(u0.w), bfhi(u0.w)};
        a1[0] += nn1 * (f32x2){bflo(u1.x), bfhi(u1.x)};
        a1[1] += nn1 * (f32x2){bflo(u1.y), bfhi(u1.y)};
        a1[2] += nn1 * (f32x2){bflo(u1.z), bfhi(u1.z)};
        a1[3] += nn1 * (f32x2){bflo(u1.w), bfhi(u1.w)};
        a2[0] += nn2 * (f32x2){bflo(u2.x), bfhi(u2.x)};
        a2[1] += nn2 * (f32x2){bflo(u2.y), bfhi(u2.y)};
        a2[2] += nn2 * (f32x2){bflo(u2.z), bfhi(u2.z)};
        a2[3] += nn2 * (f32x2){bflo(u2.w), bfhi(u2.w)};
        a3[0] += nn3 * (f32x2){bflo(u3.x), bfhi(u3.x)};
        a3[1] += nn3 * (f32x2){bflo(u3.y), bfhi(u3.y)};
        a3[2] += nn3 * (f32x2){bflo(u3.z), bfhi(u3.z)};
        a3[3] += nn3 * (f32x2){bflo(u3.w), bfhi(u3.w)};
    }
    uint4 su = *(const uint4*)(xb + node * 16 + qoff);
    float dn2 = dn * dn;
    f32x2 nd = {dn2, dn2};
    a0[0] += nd * (f32x2){bflo(su.x), bfhi(su.x)};
    a0[1] += nd * (f32x2){bflo(su.y), bfhi(su.y)};
    a0[2] += nd * (f32x2){bflo(su.z), bfhi(su.z)};
    a0[3] += nd * (f32x2){bflo(su.w), bfhi(su.w)};
    float4 o0, o1;
    f32x2 s0 = (a0[0] + a1[0]) + (a2[0] + a3[0]);
    f32x2 s1 = (a0[1] + a1[1]) + (a2[1] + a3[1]);
    f32x2 s2 = (a0[2] + a1[2]) + (a2[2] + a3[2]);
    f32x2 s3 = (a0[3] + a1[3]) + (a2[3] + a3[3]);
    o0.x = s0[0]; o0.y = s0[1]; o0.z = s1[0]; o0.w = s1[1];
    o1.x = s2[0]; o1.y = s2[1]; o1.z = s3[0]; o1.w = s3[1];
    *(float4*)(aggx + node * 16 + qoff) = o0;       // 64 B row = 1 full line
    *(float4*)(aggx + node * 16 + qoff + 4) = o1;
}

// ---- h1 = relu(aggx[:, :12] @ W1 + b1) -> bf16 ----
__global__ void w1_kernel(const float* __restrict__ aggx, const float* __restrict__ W1,
                          const float* __restrict__ b1, unsigned short* __restrict__ h) {
    __shared__ float sW[IN_CH * HID];
    __shared__ float sA[256];
    int tid = threadIdx.x;
    for (int i = tid; i < IN_CH * HID; i += 256) sW[i] = W1[i];
    int node0 = blockIdx.x * 16;
    sA[tid] = aggx[node0 * 16 + tid];
    __syncthreads();
    int nl = tid >> 4, c4 = (tid & 15) * 4;
    float a0 = 0, a1 = 0, a2 = 0, a3 = 0;
#pragma unroll
    for (int k = 0; k < IN_CH; k++) {
        float av = sA[nl * 16 + k];
        const float* w = &sW[k * HID + c4];
        a0 += av * w[0]; a1 += av * w[1]; a2 += av * w[2]; a3 += av * w[3];
    }
    const float* bb = &b1[c4];
    ushort4 v = {f2bf(fmaxf(a0 + bb[0], 0.0f)), f2bf(fmaxf(a1 + bb[1], 0.0f)),
                 f2bf(fmaxf(a2 + bb[2], 0.0f)), f2bf(fmaxf(a3 + bb[3], 0.0f))};
    *(ushort4*)&h[(node0 + nl) * HID + c4] = v;
}

// ---- layer-2 gather body: 8 gathers in flight per subgroup (x4-padded rows) ----
__device__ __forceinline__ void agg_body(int beg, int end, const int2* __restrict__ csr,
                                         const unsigned short* __restrict__ h,
                                         int qoff, float* r) {
    f32x2 a0[4] = {{0, 0}, {0, 0}, {0, 0}, {0, 0}};
    f32x2 a1[4] = {{0, 0}, {0, 0}, {0, 0}, {0, 0}};
    f32x2 a2[4] = {{0, 0}, {0, 0}, {0, 0}, {0, 0}};
    f32x2 a3[4] = {{0, 0}, {0, 0}, {0, 0}, {0, 0}};
    int j = beg;
    for (; j + 8 <= end; j += 8) {  // 8 edges in flight
        int4 e01 = *(const int4*)(csr + j);
        int4 e23 = *(const int4*)(csr + j + 2);
        int4 e45 = *(const int4*)(csr + j + 4);
        int4 e67 = *(const int4*)(csr + j + 6);
        uint4 u0 = *(const uint4*)(h + e01.x + qoff);
        uint4 u1 = *(const uint4*)(h + e01.z + qoff);
        uint4 u2 = *(const uint4*)(h + e23.x + qoff);
        uint4 u3 = *(const uint4*)(h + e23.z + qoff);
        uint4 u4 = *(const uint4*)(h + e45.x + qoff);
        uint4 u5 = *(const uint4*)(h + e45.z + qoff);
        uint4 u6 = *(const uint4*)(h + e67.x + qoff);
        uint4 u7 = *(const uint4*)(h + e67.z + qoff);
        float n0 = __int_as_float(e01.y), n1 = __int_as_float(e01.w);
        float n2 = __int_as_float(e23.y), n3 = __int_as_float(e23.w);
        float n4 = __int_as_float(e45.y), n5 = __int_as_float(e45.w);
        float n6 = __int_as_float(e67.y), n7 = __int_as_float(e67.w);
        f32x2 nn0 = {n0, n0}, nn1 = {n1, n1}, nn2 = {n2, n2}, nn3 = {n3, n3};
        f32x2 nn4 = {n4, n4}, nn5 = {n5, n5}, nn6 = {n6, n6}, nn7 = {n7, n7};
        a0[0] += nn0 * (f32x2){bflo(u0.x), bfhi(u0.x)};
        a0[1] += nn0 * (f32x2){bflo(u0.y), bfhi(u0.y)};
        a0[2] += nn0 * (f32x2){bflo(u0.z), bfhi(u0.z)};
        a0[3] += nn0 * (f32x2){bflo(u0.w), bfhi(u0.w)};
        a1[0] += nn1 * (f32x2){bflo(u1.x), bfhi(u1.x)};
        a1[1] += nn1 * (f32x2){bflo(u1.y), bfhi(u1.y)};
        a1[2] += nn1 * (f32x2){bflo(u1.z), bfhi(u1.z)};
        a1[3] += nn1 * (f32x2){bflo(u1.w), bfhi(u1.w)};
        a2[0] += nn2 * (f32x2){bflo(u2.x), bfhi(u2.x)};
        a2[1] += nn2 * (f32x2){bflo(u2.y), bfhi(u2.y)};
        a2[2] += nn2 * (f32x2){bflo(u2.z), bfhi(u2.z)};
        a2[3] += nn2 * (f32x2){bflo(u2.w), bfhi(u2.w)};
        a3[0] += nn3 * (f32x2){bflo(u3.x), bfhi(u3.x)};
        a3[1] += nn3 * (f32x2){bflo(u3.y), bfhi(u3.y)};
        a3[2] += nn3 * (f32x2){bflo(u3.z), bfhi(u3.z)};
        a3[3] += nn3 * (f32x2){bflo(u3.w), bfhi(u3.w)};
        a0[0] += nn4 * (f32x2){bflo(u4.x), bfhi(u4.x)};
        a0[1] += nn4 * (f32x2){bflo(u4.y), bfhi(u4.y)};
        a0[2] += nn4 * (f32x2){bflo(u4.z), bfhi(u4.z)};
        a0[3] += nn4 * (f32x2){bflo(u4.w), bfhi(u4.w)};
        a1[0] += nn5 * (f32x2){bflo(u5.x), bfhi(u5.x)};
        a1[1] += nn5 * (f32x2){bflo(u5.y), bfhi(u5.y)};
        a1[2] += nn5 * (f32x2){bflo(u5.z), bfhi(u5.z)};
        a1[3] += nn5 * (f32x2){bflo(u5.w), bfhi(u5.w)};
        a2[0] += nn6 * (f32x2){bflo(u6.x), bfhi(u6.x)};
        a2[1] += nn6 * (f32x2){bflo(u6.y), bfhi(u6.y)};
        a2[2] += nn6 * (f32x2){bflo(u6.z), bfhi(u6.z)};
        a2[3] += nn6 * (f32x2){bflo(u6.w), bfhi(u6.w)};
        a3[0] += nn7 * (f32x2){bflo(u7.x), bfhi(u7.x)};
        a3[1] += nn7 * (f32x2){bflo(u7.y), bfhi(u7.y)};
        a3[2] += nn7 * (f32x2){bflo(u7.z), bfhi(u7.z)};
        a3[3] += nn7 * (f32x2){bflo(u7.w), bfhi(u7.w)};
    }
    if (j < end) {  // exactly 4 padded edges remain
        int4 e01 = *(const int4*)(csr + j);
        int4 e23 = *(const int4*)(csr + j + 2);
        uint4 u0 = *(const uint4*)(h + e01.x + qoff);
        uint4 u1 = *(const uint4*)(h + e01.z + qoff);
        uint4 u2 = *(const uint4*)(h + e23.x + qoff);
        uint4 u3 = *(const uint4*)(h + e23.z + qoff);
        float n0 = __int_as_float(e01.y), n1 = __int_as_float(e01.w);
        float n2 = __int_as_float(e23.y), n3 = __int_as_float(e23.w);
        f32x2 nn0 = {n0, n0}, nn1 = {n1, n1}, nn2 = {n2, n2}, nn3 = {n3, n3};
        a0[0] += nn0 * (f32x2){bflo(u0.x), bfhi(u0.x)};
        a0[1] += nn0 * (f32x2){bflo(u0.y), bfhi(u0.y)};
        a0[2] += nn0 * (f32x2){bflo(u0.z), bfhi(u0.z)};
        a0[3] += nn0 * (f32x2){bflo(u0.w), bfhi(u0.w)};
        a1[0] += nn1 * (f32x2){bflo(u1.x), bfhi(u1.x)};
        a1[1] += nn1 * (f32x2){bflo(u1.y), bfhi(u1.y)};
        a1[2] += nn1 * (f32x2){bflo(u1.z), bfhi(u1.z)};
        a1[3] += nn1 * (f32x2){bflo(u1.w), bfhi(u1.w)};
        a2[0] += nn2 * (f32x2){bflo(u2.x), bfhi(u2.x)};
        a2[1] += nn2 * (f32x2){bflo(u2.y), bfhi(u2.y)};
        a2[2] += nn2 * (f32x2){bflo(u2.z), bfhi(u2.z)};
        a2[3] += nn2 * (f32x2){bflo(u2.w), bfhi(u2.w)};
        a3[0] += nn3 * (f32x2){bflo(u3.x), bfhi(u3.x)};
        a3[1] += nn3 * (f32x2){bflo(u3.y), bfhi(u3.y)};
        a3[2] += nn3 * (f32x2){bflo(u3.z), bfhi(u3.z)};
        a3[3] += nn3 * (f32x2){bflo(u3.w), bfhi(u3.w)};
    }
#pragma unroll
    for (int k = 0; k < 4; k++) {
        f32x2 s = (a0[k] + a1[k]) + (a2[k] + a3[k]);
        r[2 * k] = s[0];
        r[2 * k + 1] = s[1];
    }
}

// ---- layer-2 gather-aggregate + relu + fused mean-pool (run-length flush) ----
__global__ void agg_pool_kernel(const int2* __restrict__ rowbounds, const int2* __restrict__ csr,
                                const float* __restrict__ dinv,
                                const unsigned short* __restrict__ h,
                                const float* __restrict__ b, const int* __restrict__ batch,
                                float* __restrict__ pool, float* __restrict__ gcnt) {
    __shared__ float red[32][HID];  // 8 KB
    __shared__ int gids[32];
    int tid = threadIdx.x;
    int w = tid >> 6, lane = tid & 63, sub = lane >> 3, q = lane & 7;
    int qoff = 8 * q;
    int node = (blockIdx.x * 4 + w) * 8 + sub;
    int2 rb = rowbounds[node];
    float dn = dinv[node];
    float r[8];
    agg_body(rb.x, rb.y, csr, h, qoff, r);
    uint4 su = *(const uint4*)(h + node * HID + qoff);
    float4 b0 = *(const float4*)&b[qoff];
    float4 b1 = *(const float4*)&b[qoff + 4];
    float dn2 = dn * dn;
    float4 v0, v1;
    v0.x = fmaxf(r[0] + dn2 * bflo(su.x) + b0.x, 0.0f);
    v0.y = fmaxf(r[1] + dn2 * bfhi(su.x) + b0.y, 0.0f);
    v0.z = fmaxf(r[2] + dn2 * bflo(su.y) + b0.z, 0.0f);
    v0.w = fmaxf(r[3] + dn2 * bfhi(su.y) + b0.w, 0.0f);
    v1.x = fmaxf(r[4] + dn2 * bflo(su.z) + b1.x, 0.0f);
    v1.y = fmaxf(r[5] + dn2 * bfhi(su.z) + b1.y, 0.0f);
    v1.z = fmaxf(r[6] + dn2 * bflo(su.w) + b1.z, 0.0f);
    v1.w = fmaxf(r[7] + dn2 * bfhi(su.w) + b1.w, 0.0f);
    int nl = w * 8 + sub;
    *(float4*)&red[nl][qoff] = v0;
    *(float4*)&red[nl][qoff + 4] = v1;
    if (q == 0) gids[nl] = batch[node];
    __syncthreads();
    if (tid < 64) {  // wave 0: run-length reduce 32 nodes (batch sorted)
        int c = tid;
        float acc = 0.0f;
        int cur = gids[0], cnt = 0;
        for (int n = 0; n < 32; n++) {
            int g = gids[n];
            if (g != cur) {
                atomicAdd(&pool[cur * HID + c], acc);
                if (c == 0) atomicAdd(&gcnt[cur], (float)cnt);
                acc = 0.0f; cnt = 0; cur = g;
            }
            acc += red[n][c];
            cnt++;
        }
        atomicAdd(&pool[cur * HID + c], acc);
        if (c == 0) atomicAdd(&gcnt[cur], (float)cnt);
    }
}

// ---- h @ W2 : [N,64] @ [64,64], bf16 in/out, fp32 compute ----
__global__ void hw2_kernel(const unsigned short* __restrict__ hin,
                           const float* __restrict__ W2, unsigned short* __restrict__ hout) {
    __shared__ float sW[HID * HID];
    __shared__ __align__(16) float sh[16 * HID];
    int tid = threadIdx.x;
    for (int i = tid; i < HID * HID; i += 256) sW[i] = W2[i];
    int node0 = blockIdx.x * 16;
    {
        uint2 u = *(const uint2*)&hin[node0 * HID + 4 * tid];
        sh[4 * tid + 0] = bflo(u.x); sh[4 * tid + 1] = bfhi(u.x);
        sh[4 * tid + 2] = bflo(u.y); sh[4 * tid + 3] = bfhi(u.y);
    }
    __syncthreads();
    int nl = tid >> 4, c4 = (tid & 15) * 4;
    float a0 = 0, a1 = 0, a2 = 0, a3 = 0;
#pragma unroll 8
    for (int k = 0; k < HID; k++) {
        float hv = sh[nl * HID + k];
        float4 w = *(const float4*)&sW[k * HID + c4];
        a0 += hv * w.x; a1 += hv * w.y; a2 += hv * w.z; a3 += hv * w.w;
    }
    ushort4 v = {f2bf(a0), f2bf(a1), f2bf(a2), f2bf(a3)};
    *(ushort4*)&hout[(node0 + nl) * HID + c4] = v;
}

// ---- final: out = sigmoid((pool/cnt) @ Wfc + bfc) ----
__global__ void final_kernel(const float* __restrict__ pool, const float* __restrict__ gcnt,
                             const float* __restrict__ Wfc, const float* __restrict__ bfc,
                             float* __restrict__ out) {
    int idx = blockIdx.x * 256 + threadIdx.x;
    if (idx >= N_GRAPHS * OUT_CH) return;
    int g = idx >> 2, o = idx & 3;
    float inv = 1.0f / fmaxf(gcnt[g], 1.0f);
    float acc = bfc[o];
#pragma unroll
    for (int k = 0; k < HID; k++) acc += pool[g * HID + k] * inv * Wfc[k * OUT_CH + o];
    out[idx] = 1.0f / (1.0f + expf(-acc));
}

extern "C" void kernel_launch(void* const* d_in, const int* in_sizes, int n_in,
                              void* d_out, int out_size, void* d_ws, size_t ws_size,
                              hipStream_t stream) {
    const float* x   = (const float*)d_in[0];
    const int* eidx  = (const int*)d_in[1];
    const int* batch = (const int*)d_in[2];
    const float* W1  = (const float*)d_in[3];
    const float* b1  = (const float*)d_in[4];
    const float* W2  = (const float*)d_in[5];
    const float* b2  = (const float*)d_in[6];
    const float* Wfc = (const float*)d_in[7];
    const float* bfc = (const float*)d_in[8];
    float* out = (float*)d_out;

    const int* src = eidx;
    const int* dst = eidx + N_EDGES;

    // workspace layout (~77 MB)
    unsigned short* hA = (unsigned short*)d_ws;              // 16 MB bf16 (h1)
    unsigned short* hB = hA + (size_t)N_NODES * HID;         // 16 MB bf16 (h1@W2)
    int2*  csr    = (int2*)(hB + (size_t)N_NODES * HID);     // 21 MB {src<<6, norm}
    int*   staged = (int*)(csr + (size_t)NBUCK * CSR_STRIDE); // 9.4 MB bucket-strided
    float* dinv   = (float*)(staged + (size_t)NBUCK * STRIDE); // 512 KB
    int2*  rowbounds = (int2*)(dinv + N_NODES);              // 1 MB
    int*   bucket_count = (int*)(rowbounds + N_NODES);       // 2 KB
    float* pool   = (float*)(bucket_count + NBUCK);          // 512 KB
    float* gcnt   = pool + N_GRAPHS * HID;                   // 8 KB
    unsigned short* xb = (unsigned short*)(gcnt + N_GRAPHS); // 4 MB bf16 [N,16]
    float* aggx   = (float*)(xb + (size_t)N_NODES * 16);     // 8 MB fp32 [N,16]

    hipMemsetAsync(bucket_count, 0, (size_t)NBUCK * 4, stream);
    hipMemsetAsync(pool, 0, (size_t)(N_GRAPHS * HID + N_GRAPHS) * 4, stream);

    // CSR build: bucket sort -> padded rowbounds/dinv -> ordered fill (+pads)
    bucket_kernel<<<N_EDGES / CHUNK, 1024, 0, stream>>>(src, dst, bucket_count, staged);
    count_kernel<<<NBUCK, 256, 0, stream>>>(bucket_count, staged, rowbounds, dinv);
    place_kernel<<<NBUCK, 256, 0, stream>>>(bucket_count, staged, rowbounds, dinv, csr);

    // layer 1: agg(x) @ W1 (aggregation commutes with the linear map)
    xcast_kernel<<<N_NODES / 256, 256, 0, stream>>>(x, xb);
    agg_x_kernel<<<N_NODES / 128, 256, 0, stream>>>(rowbounds, csr, dinv, xb, aggx);
    w1_kernel<<<N_NODES / 16, 256, 0, stream>>>(aggx, W1, b1, hA);

    // layer 2 (pool fused; h2 never materialized)
    hw2_kernel<<<N_NODES / 16, 256, 0, stream>>>(hA, W2, hB);
    agg_pool_kernel<<<N_NODES / 32, 256, 0, stream>>>(rowbounds, csr, dinv, hB, b2, batch,
                                                      pool, gcnt);

    // head
    final_kernel<<<(N_GRAPHS * OUT_CH + 255) / 256, 256, 0, stream>>>(pool, gcnt, Wfc, bfc, out);
}

// Round 15
// 229.690 us; speedup vs baseline: 1.4322x; 1.0107x over previous
//
#include <hip/hip_runtime.h>
#include <hip/hip_bf16.h>

// GCN. CSR via 2-pass LDS bucket sort (wave-contiguous global writes only).
// Layer 1: agg(xW)=agg(x)W over a 4 MB bf16 x-table. Layer 2: the gathered
// table hB=h1@W2 is stored FP8 e4m3 (8 MB, one 64B line per row) — R14 showed
// the gather is pinned at the per-CU miss-service ceiling (44 us for a 16 MB
// table, invariant to ILP/order/occupancy), so halving the table is the only
// remaining lever. fp32 accumulate everywhere; HW cvt_pk fp8<->f32.

#define N_NODES 131072
#define N_EDGES 2097152
#define N_GRAPHS 2048
#define IN_CH 12
#define HID 64
#define OUT_CH 4
#define NBUCK 512          // buckets of 256 dst nodes
#define CHUNK 8192         // edges per bucket_kernel block
#define STRIDE 4608        // staging capacity per bucket (mean 4096, sd 64)
#define CSR_STRIDE 5120    // csr capacity per bucket (padded mean ~4500)
#define CAP 5120           // place_kernel LDS image capacity (40 KB)

typedef float f32x2 __attribute__((ext_vector_type(2)));

__device__ __forceinline__ unsigned short f2bf(float f) {
    unsigned u = __float_as_uint(f);
    return (unsigned short)((u + 0x7fffu + ((u >> 16) & 1u)) >> 16);  // RNE
}
__device__ __forceinline__ unsigned pack2bf(float lo, float hi) {
    return (unsigned)f2bf(lo) | ((unsigned)f2bf(hi) << 16);
}
__device__ __forceinline__ float bflo(unsigned v) { return __uint_as_float(v << 16); }
__device__ __forceinline__ float bfhi(unsigned v) { return __uint_as_float(v & 0xFFFF0000u); }

// ---- pass A: LDS bucket sort of edges by dst>>8 into strided staging ----
__global__ __launch_bounds__(1024, 4)
void bucket_kernel(const int* __restrict__ src, const int* __restrict__ dst,
                   int* __restrict__ bucket_count, int* __restrict__ staged) {
    __shared__ int hist[NBUCK];
    __shared__ int lscan[NBUCK];
    __shared__ int gbase[NBUCK];
    __shared__ int cursor[NBUCK];
    __shared__ int sorted[CHUNK];  // 32 KB
    int tid = threadIdx.x;
    int base = blockIdx.x * CHUNK;
    if (tid < NBUCK) { hist[tid] = 0; cursor[tid] = 0; }
    __syncthreads();
    int d8[8], s8[8];
#pragma unroll
    for (int k = 0; k < 8; k++) {
        int i = base + k * 1024 + tid;
        d8[k] = dst[i];
        s8[k] = src[i];
        atomicAdd(&hist[d8[k] >> 8], 1);
    }
    __syncthreads();
    if (tid < NBUCK) lscan[tid] = hist[tid];
    __syncthreads();
    for (int off = 1; off < NBUCK; off <<= 1) {
        int u = (tid < NBUCK && tid >= off) ? lscan[tid - off] : 0;
        __syncthreads();
        if (tid < NBUCK) lscan[tid] += u;
        __syncthreads();
    }
    if (tid < NBUCK) gbase[tid] = atomicAdd(&bucket_count[tid], hist[tid]);
    __syncthreads();
#pragma unroll
    for (int k = 0; k < 8; k++) {
        int b = d8[k] >> 8;
        int start = lscan[b] - hist[b];
        int p = start + atomicAdd(&cursor[b], 1);
        sorted[p] = ((d8[k] & 255) << 17) | s8[k];
    }
    __syncthreads();
    int wid = tid >> 6, lane = tid & 63;
    int g16 = lane >> 4, k16 = lane & 15;
    for (int b0 = wid * 4; b0 < NBUCK; b0 += 64) {
        int b = b0 + g16;
        int cb = hist[b];
        int lbase = lscan[b] - cb;
        int gb = b * STRIDE + gbase[b];
        for (int k = k16; k < cb; k += 16) staged[gb + k] = sorted[lbase + k];
    }
}

// ---- per-bucket: degree count -> padded rowbounds, dinv; + x->bf16 cast ----
__global__ void count_kernel(const int* __restrict__ bucket_count, const int* __restrict__ staged,
                             int2* __restrict__ rowbounds, float* __restrict__ dinv,
                             const float* __restrict__ x, unsigned short* __restrict__ xb) {
    __shared__ int cnt[256];
    __shared__ int scn[256];
    int b = blockIdx.x;
    int tid = threadIdx.x;
    int count = bucket_count[b];
    const int* st = staged + b * STRIDE;
    cnt[tid] = 0;
    __syncthreads();
    for (int i = tid; i < count; i += 256) atomicAdd(&cnt[(st[i] >> 17) & 255], 1);
    __syncthreads();
    int deg = cnt[tid];
    int degp = (deg + 3) & ~3;  // pad to x4
    scn[tid] = degp;
    __syncthreads();
    for (int off = 1; off < 256; off <<= 1) {
        int u = (tid >= off) ? scn[tid - off] : 0;
        __syncthreads();
        scn[tid] += u;
        __syncthreads();
    }
    int nbase = (b << 8) + tid;
    int gbeg = b * CSR_STRIDE + scn[tid] - degp;
    rowbounds[nbase] = make_int2(gbeg, gbeg + degp);
    dinv[nbase] = rsqrtf((float)deg + 1.0f);
    // fused xcast: this block also casts node nbase's features
    const float* xp = x + nbase * IN_CH;
    unsigned o[8];
#pragma unroll
    for (int k = 0; k < 6; k++) o[k] = pack2bf(xp[2 * k], xp[2 * k + 1]);
    o[6] = 0; o[7] = 0;
    uint4* dstp = (uint4*)(xb + nbase * 16);
    dstp[0] = make_uint4(o[0], o[1], o[2], o[3]);
    dstp[1] = make_uint4(o[4], o[5], o[6], o[7]);
}

// ---- per-bucket: place records (+zero pads) into CSR via LDS image ----
__global__ void place_kernel(const int* __restrict__ bucket_count, const int* __restrict__ staged,
                             const int2* __restrict__ rowbounds, const float* __restrict__ dinv,
                             int2* __restrict__ csr) {
    __shared__ int loff[256];
    __shared__ int cursor[256];
    __shared__ float ldinv[256];
    __shared__ int totalS;
    __shared__ int2 image[CAP];  // 40 KB
    int b = blockIdx.x;
    int tid = threadIdx.x;
    int nbase = (b << 8) + tid;
    int gb = b * CSR_STRIDE;
    int count = bucket_count[b];
    int2 rb = rowbounds[nbase];
    int lo = rb.x - gb;
    int degp = rb.y - rb.x;
    loff[tid] = lo;
    cursor[tid] = 0;
    ldinv[tid] = dinv[nbase];
    if (tid == 255) totalS = lo + degp;
    __syncthreads();
    const int* st = staged + b * STRIDE;
    for (int i = tid; i < count; i += 256) {
        int rec = st[i];
        int s = rec & 0x1FFFF;
        int dq = (rec >> 17) & 255;
        float norm = dinv[s] * ldinv[dq];  // dinv 512 KB -> L2-resident
        int p = loff[dq] + atomicAdd(&cursor[dq], 1);
        int2 val = make_int2(s << 6, __float_as_int(norm));  // s*64: byte off (fp8) / x16-row (bf16 x)
        if (p < CAP) image[p] = val;
        else csr[gb + p] = val;
    }
    __syncthreads();
    for (int p = lo + cursor[tid]; p < lo + degp; p++) {
        int2 z = make_int2(0, 0);
        if (p < CAP) image[p] = z;
        else csr[gb + p] = z;
    }
    __syncthreads();
    int lim = totalS < CAP ? totalS : CAP;
    int2* dstp = csr + gb;
    for (int i = tid; i < lim; i += 256) dstp[i] = image[i];
}

// ---- layer-1 aggregation over x table: wave = 32 nodes, 2-lane subgroups ----
__global__ void agg_x_kernel(const int2* __restrict__ rowbounds, const int2* __restrict__ csr,
                             const float* __restrict__ dinv,
                             const unsigned short* __restrict__ xb, float* __restrict__ aggx) {
    int tid = threadIdx.x;
    int w = tid >> 6, lane = tid & 63, sub = lane >> 1, p = lane & 1;
    int qoff = 8 * p;
    int node = (blockIdx.x * 4 + w) * 32 + sub;
    int2 rb = rowbounds[node];
    float dn = dinv[node];
    f32x2 a0[4] = {{0, 0}, {0, 0}, {0, 0}, {0, 0}};
    f32x2 a1[4] = {{0, 0}, {0, 0}, {0, 0}, {0, 0}};
    f32x2 a2[4] = {{0, 0}, {0, 0}, {0, 0}, {0, 0}};
    f32x2 a3[4] = {{0, 0}, {0, 0}, {0, 0}, {0, 0}};
    for (int j = rb.x; j < rb.y; j += 4) {  // padded x4: no remainder
        int4 e01 = *(const int4*)(csr + j);
        int4 e23 = *(const int4*)(csr + j + 2);
        uint4 u0 = *(const uint4*)(xb + (e01.x >> 2) + qoff);  // s*64>>2 = x16 row
        uint4 u1 = *(const uint4*)(xb + (e01.z >> 2) + qoff);
        uint4 u2 = *(const uint4*)(xb + (e23.x >> 2) + qoff);
        uint4 u3 = *(const uint4*)(xb + (e23.z >> 2) + qoff);
        float n0 = __int_as_float(e01.y), n1 = __int_as_float(e01.w);
        float n2 = __int_as_float(e23.y), n3 = __int_as_float(e23.w);
        f32x2 nn0 = {n0, n0}, nn1 = {n1, n1}, nn2 = {n2, n2}, nn3 = {n3, n3};
        a0[0] += nn0 * (f32x2){bflo(u0.x), bfhi(u0.x)};
        a0[1] += nn0 * (f32x2){bflo(u0.y), bfhi(u0.y)};
        a0[2] += nn0 * (f32x2){bflo(u0.z), bfhi(u0.z)};
        a0[3] += nn0 * (f32x2){bflo(u0.w), bfhi(u0.w)};
        a1[0] += nn1 * (f32x2){bflo(u1.x), bfhi(u1.x)};
        a1[1] += nn1 * (f32x2){bflo(u1.y), bfhi(u1.y)};
        a1[2] += nn1 * (f32x2){bflo(u1.z), bfhi(u1.z)};
        a1[3] += nn1 * (f32x2){bflo(u1.w), bfhi(u1.w)};
        a2[0] += nn2 * (f32x2){bflo(u2.x), bfhi(u2.x)};
        a2[1] += nn2 * (f32x2){bflo(u2.y), bfhi(u2.y)};
        a2[2] += nn2 * (f32x2){bflo(u2.z), bfhi(u2.z)};
        a2[3] += nn2 * (f32x2){bflo(u2.w), bfhi(u2.w)};
        a3[0] += nn3 * (f32x2){bflo(u3.x), bfhi(u3.x)};
        a3[1] += nn3 * (f32x2){bflo(u3.y), bfhi(u3.y)};
        a3[2] += nn3 * (f32x2){bflo(u3.z), bfhi(u3.z)};
        a3[3] += nn3 * (f32x2){bflo(u3.w), bfhi(u3.w)};
    }
    uint4 su = *(const uint4*)(xb + node * 16 + qoff);
    float dn2 = dn * dn;
    f32x2 nd = {dn2, dn2};
    a0[0] += nd * (f32x2){bflo(su.x), bfhi(su.x)};
    a0[1] += nd * (f32x2){bflo(su.y), bfhi(su.y)};
    a0[2] += nd * (f32x2){bflo(su.z), bfhi(su.z)};
    a0[3] += nd * (f32x2){bflo(su.w), bfhi(su.w)};
    float4 o0, o1;
    f32x2 s0 = (a0[0] + a1[0]) + (a2[0] + a3[0]);
    f32x2 s1 = (a0[1] + a1[1]) + (a2[1] + a3[1]);
    f32x2 s2 = (a0[2] + a1[2]) + (a2[2] + a3[2]);
    f32x2 s3 = (a0[3] + a1[3]) + (a2[3] + a3[3]);
    o0.x = s0[0]; o0.y = s0[1]; o0.z = s1[0]; o0.w = s1[1];
    o1.x = s2[0]; o1.y = s2[1]; o1.z = s3[0]; o1.w = s3[1];
    *(float4*)(aggx + node * 16 + qoff) = o0;       // 64 B row = 1 full line
    *(float4*)(aggx + node * 16 + qoff + 4) = o1;
}

// ---- h1 = relu(aggx[:, :12] @ W1 + b1) -> bf16 ----
__global__ void w1_kernel(const float* __restrict__ aggx, const float* __restrict__ W1,
                          const float* __restrict__ b1, unsigned short* __restrict__ h) {
    __shared__ float sW[IN_CH * HID];
    __shared__ float sA[256];
    int tid = threadIdx.x;
    for (int i = tid; i < IN_CH * HID; i += 256) sW[i] = W1[i];
    int node0 = blockIdx.x * 16;
    sA[tid] = aggx[node0 * 16 + tid];
    __syncthreads();
    int nl = tid >> 4, c4 = (tid & 15) * 4;
    float a0 = 0, a1 = 0, a2 = 0, a3 = 0;
#pragma unroll
    for (int k = 0; k < IN_CH; k++) {
        float av = sA[nl * 16 + k];
        const float* w = &sW[k * HID + c4];
        a0 += av * w[0]; a1 += av * w[1]; a2 += av * w[2]; a3 += av * w[3];
    }
    const float* bb = &b1[c4];
    ushort4 v = {f2bf(fmaxf(a0 + bb[0], 0.0f)), f2bf(fmaxf(a1 + bb[1], 0.0f)),
                 f2bf(fmaxf(a2 + bb[2], 0.0f)), f2bf(fmaxf(a3 + bb[3], 0.0f))};
    *(ushort4*)&h[(node0 + nl) * HID + c4] = v;
}

// ---- hB = h1 @ W2 -> fp8 e4m3 (the gathered table; 64 B/row = 1 line) ----
__global__ void hw2_kernel(const unsigned short* __restrict__ hin,
                           const float* __restrict__ W2, unsigned int* __restrict__ hout) {
    __shared__ float sW[HID * HID];
    __shared__ __align__(16) float sh[16 * HID];
    int tid = threadIdx.x;
    for (int i = tid; i < HID * HID; i += 256) sW[i] = W2[i];
    int node0 = blockIdx.x * 16;
    {
        uint2 u = *(const uint2*)&hin[node0 * HID + 4 * tid];
        sh[4 * tid + 0] = bflo(u.x); sh[4 * tid + 1] = bfhi(u.x);
        sh[4 * tid + 2] = bflo(u.y); sh[4 * tid + 3] = bfhi(u.y);
    }
    __syncthreads();
    int nl = tid >> 4, c4 = (tid & 15) * 4;
    float a0 = 0, a1 = 0, a2 = 0, a3 = 0;
#pragma unroll 8
    for (int k = 0; k < HID; k++) {
        float hv = sh[nl * HID + k];
        float4 w = *(const float4*)&sW[k * HID + c4];
        a0 += hv * w.x; a1 += hv * w.y; a2 += hv * w.z; a3 += hv * w.w;
    }
    unsigned int packed = (unsigned int)__builtin_amdgcn_cvt_pk_fp8_f32(a0, a1, 0, false);
    packed = (unsigned int)__builtin_amdgcn_cvt_pk_fp8_f32(a2, a3, (int)packed, true);
    hout[((node0 + nl) * HID + c4) >> 2] = packed;  // 4 B/thread, coalesced
}

// ---- layer-2 fp8 gather body: 8 gathers in flight; lane = 8 ch (uint2, 8 B) ----
__device__ __forceinline__ void fma_fp8(f32x2* a, uint2 u, float n) {
    f32x2 nn = {n, n};
    a[0] += nn * __builtin_amdgcn_cvt_pk_f32_fp8((int)u.x, false);
    a[1] += nn * __builtin_amdgcn_cvt_pk_f32_fp8((int)u.x, true);
    a[2] += nn * __builtin_amdgcn_cvt_pk_f32_fp8((int)u.y, false);
    a[3] += nn * __builtin_amdgcn_cvt_pk_f32_fp8((int)u.y, true);
}

__device__ __forceinline__ void agg_body(int beg, int end, const int2* __restrict__ csr,
                                         const unsigned char* __restrict__ h,
                                         int qoff, float* r) {
    f32x2 a0[4] = {{0, 0}, {0, 0}, {0, 0}, {0, 0}};
    f32x2 a1[4] = {{0, 0}, {0, 0}, {0, 0}, {0, 0}};
    f32x2 a2[4] = {{0, 0}, {0, 0}, {0, 0}, {0, 0}};
    f32x2 a3[4] = {{0, 0}, {0, 0}, {0, 0}, {0, 0}};
    int j = beg;
    for (; j + 8 <= end; j += 8) {  // 8 edges in flight
        int4 e01 = *(const int4*)(csr + j);
        int4 e23 = *(const int4*)(csr + j + 2);
        int4 e45 = *(const int4*)(csr + j + 4);
        int4 e67 = *(const int4*)(csr + j + 6);
        uint2 u0 = *(const uint2*)(h + e01.x + qoff);
        uint2 u1 = *(const uint2*)(h + e01.z + qoff);
        uint2 u2 = *(const uint2*)(h + e23.x + qoff);
        uint2 u3 = *(const uint2*)(h + e23.z + qoff);
        uint2 u4 = *(const uint2*)(h + e45.x + qoff);
        uint2 u5 = *(const uint2*)(h + e45.z + qoff);
        uint2 u6 = *(const uint2*)(h + e67.x + qoff);
        uint2 u7 = *(const uint2*)(h + e67.z + qoff);
        fma_fp8(a0, u0, __int_as_float(e01.y));
        fma_fp8(a1, u1, __int_as_float(e01.w));
        fma_fp8(a2, u2, __int_as_float(e23.y));
        fma_fp8(a3, u3, __int_as_float(e23.w));
        fma_fp8(a0, u4, __int_as_float(e45.y));
        fma_fp8(a1, u5, __int_as_float(e45.w));
        fma_fp8(a2, u6, __int_as_float(e67.y));
        fma_fp8(a3, u7, __int_as_float(e67.w));
    }
    if (j < end) {  // exactly 4 padded edges remain
        int4 e01 = *(const int4*)(csr + j);
        int4 e23 = *(const int4*)(csr + j + 2);
        uint2 u0 = *(const uint2*)(h + e01.x + qoff);
        uint2 u1 = *(const uint2*)(h + e01.z + qoff);
        uint2 u2 = *(const uint2*)(h + e23.x + qoff);
        uint2 u3 = *(const uint2*)(h + e23.z + qoff);
        fma_fp8(a0, u0, __int_as_float(e01.y));
        fma_fp8(a1, u1, __int_as_float(e01.w));
        fma_fp8(a2, u2, __int_as_float(e23.y));
        fma_fp8(a3, u3, __int_as_float(e23.w));
    }
#pragma unroll
    for (int k = 0; k < 4; k++) {
        f32x2 s = (a0[k] + a1[k]) + (a2[k] + a3[k]);
        r[2 * k] = s[0];
        r[2 * k + 1] = s[1];
    }
}

// ---- layer-2 gather-aggregate + relu + fused mean-pool (run-length flush) ----
__global__ void agg_pool_kernel(const int2* __restrict__ rowbounds, const int2* __restrict__ csr,
                                const float* __restrict__ dinv,
                                const unsigned char* __restrict__ h,
                                const float* __restrict__ b, const int* __restrict__ batch,
                                float* __restrict__ pool, float* __restrict__ gcnt) {
    __shared__ float red[32][HID];  // 8 KB
    __shared__ int gids[32];
    int tid = threadIdx.x;
    int w = tid >> 6, lane = tid & 63, sub = lane >> 3, q = lane & 7;
    int qoff = 8 * q;
    int node = (blockIdx.x * 4 + w) * 8 + sub;
    int2 rb = rowbounds[node];
    float dn = dinv[node];
    float r[8];
    agg_body(rb.x, rb.y, csr, h, qoff, r);
    uint2 su = *(const uint2*)(h + node * HID + qoff);
    f32x2 s0 = __builtin_amdgcn_cvt_pk_f32_fp8((int)su.x, false);
    f32x2 s1 = __builtin_amdgcn_cvt_pk_f32_fp8((int)su.x, true);
    f32x2 s2 = __builtin_amdgcn_cvt_pk_f32_fp8((int)su.y, false);
    f32x2 s3 = __builtin_amdgcn_cvt_pk_f32_fp8((int)su.y, true);
    float4 b0 = *(const float4*)&b[qoff];
    float4 b1 = *(const float4*)&b[qoff + 4];
    float dn2 = dn * dn;
    float4 v0, v1;
    v0.x = fmaxf(r[0] + dn2 * s0[0] + b0.x, 0.0f);
    v0.y = fmaxf(r[1] + dn2 * s0[1] + b0.y, 0.0f);
    v0.z = fmaxf(r[2] + dn2 * s1[0] + b0.z, 0.0f);
    v0.w = fmaxf(r[3] + dn2 * s1[1] + b0.w, 0.0f);
    v1.x = fmaxf(r[4] + dn2 * s2[0] + b1.x, 0.0f);
    v1.y = fmaxf(r[5] + dn2 * s2[1] + b1.y, 0.0f);
    v1.z = fmaxf(r[6] + dn2 * s3[0] + b1.z, 0.0f);
    v1.w = fmaxf(r[7] + dn2 * s3[1] + b1.w, 0.0f);
    int nl = w * 8 + sub;
    *(float4*)&red[nl][qoff] = v0;
    *(float4*)&red[nl][qoff + 4] = v1;
    if (q == 0) gids[nl] = batch[node];
    __syncthreads();
    if (tid < 64) {  // wave 0: run-length reduce 32 nodes (batch sorted)
        int c = tid;
        float acc = 0.0f;
        int cur = gids[0], cnt = 0;
        for (int n = 0; n < 32; n++) {
            int g = gids[n];
            if (g != cur) {
                atomicAdd(&pool[cur * HID + c], acc);
                if (c == 0) atomicAdd(&gcnt[cur], (float)cnt);
                acc = 0.0f; cnt = 0; cur = g;
            }
            acc += red[n][c];
            cnt++;
        }
        atomicAdd(&pool[cur * HID + c], acc);
        if (c == 0) atomicAdd(&gcnt[cur], (float)cnt);
    }
}

// ---- final: out = sigmoid((pool/cnt) @ Wfc + bfc) ----
__global__ void final_kernel(const float* __restrict__ pool, const float* __restrict__ gcnt,
                             const float* __restrict__ Wfc, const float* __restrict__ bfc,
                             float* __restrict__ out) {
    int idx = blockIdx.x * 256 + threadIdx.x;
    if (idx >= N_GRAPHS * OUT_CH) return;
    int g = idx >> 2, o = idx & 3;
    float inv = 1.0f / fmaxf(gcnt[g], 1.0f);
    float acc = bfc[o];
#pragma unroll
    for (int k = 0; k < HID; k++) acc += pool[g * HID + k] * inv * Wfc[k * OUT_CH + o];
    out[idx] = 1.0f / (1.0f + expf(-acc));
}

extern "C" void kernel_launch(void* const* d_in, const int* in_sizes, int n_in,
                              void* d_out, int out_size, void* d_ws, size_t ws_size,
                              hipStream_t stream) {
    const float* x   = (const float*)d_in[0];
    const int* eidx  = (const int*)d_in[1];
    const int* batch = (const int*)d_in[2];
    const float* W1  = (const float*)d_in[3];
    const float* b1  = (const float*)d_in[4];
    const float* W2  = (const float*)d_in[5];
    const float* b2  = (const float*)d_in[6];
    const float* Wfc = (const float*)d_in[7];
    const float* bfc = (const float*)d_in[8];
    float* out = (float*)d_out;

    const int* src = eidx;
    const int* dst = eidx + N_EDGES;

    // workspace layout (~70 MB)
    unsigned short* hA = (unsigned short*)d_ws;              // 16 MB bf16 (h1)
    unsigned char*  hB = (unsigned char*)(hA + (size_t)N_NODES * HID);  // 8 MB fp8 (h1@W2)
    int2*  csr    = (int2*)(hB + (size_t)N_NODES * HID);     // 21 MB {src*64, norm}
    int*   staged = (int*)(csr + (size_t)NBUCK * CSR_STRIDE); // 9.4 MB bucket-strided
    float* dinv   = (float*)(staged + (size_t)NBUCK * STRIDE); // 512 KB
    int2*  rowbounds = (int2*)(dinv + N_NODES);              // 1 MB
    int*   bucket_count = (int*)(rowbounds + N_NODES);       // 2 KB
    float* pool   = (float*)(bucket_count + NBUCK);          // 512 KB
    float* gcnt   = pool + N_GRAPHS * HID;                   // 8 KB
    unsigned short* xb = (unsigned short*)(gcnt + N_GRAPHS); // 4 MB bf16 [N,16]
    float* aggx   = (float*)(xb + (size_t)N_NODES * 16);     // 8 MB fp32 [N,16]

    hipMemsetAsync(bucket_count, 0, (size_t)NBUCK * 4, stream);
    hipMemsetAsync(pool, 0, (size_t)(N_GRAPHS * HID + N_GRAPHS) * 4, stream);

    // CSR build (+fused x->bf16 cast in count)
    bucket_kernel<<<N_EDGES / CHUNK, 1024, 0, stream>>>(src, dst, bucket_count, staged);
    count_kernel<<<NBUCK, 256, 0, stream>>>(bucket_count, staged, rowbounds, dinv, x, xb);
    place_kernel<<<NBUCK, 256, 0, stream>>>(bucket_count, staged, rowbounds, dinv, csr);

    // layer 1: agg(x) @ W1
    agg_x_kernel<<<N_NODES / 128, 256, 0, stream>>>(rowbounds, csr, dinv, xb, aggx);
    w1_kernel<<<N_NODES / 16, 256, 0, stream>>>(aggx, W1, b1, hA);

    // layer 2: hB = h1@W2 (fp8 table), then gather + pool
    hw2_kernel<<<N_NODES / 16, 256, 0, stream>>>(hA, W2, (unsigned int*)hB);
    agg_pool_kernel<<<N_NODES / 32, 256, 0, stream>>>(rowbounds, csr, dinv, hB, b2, batch,
                                                      pool, gcnt);

    // head
    final_kernel<<<(N_GRAPHS * OUT_CH + 255) / 256, 256, 0, stream>>>(pool, gcnt, Wfc, bfc, out);
}

// Round 16
// 197.104 us; speedup vs baseline: 1.6690x; 1.1653x over previous
//
#include <hip/hip_runtime.h>
#include <hip/hip_bf16.h>

// GCN. CSR via 2-pass LDS bucket sort (wave-contiguous global writes only).
// Gather tables are pre-scaled by dinv[src] -> csr stores ONLY src (4 B/edge);
// dn applied once per node. Layer 1: agg over 4 MB bf16 x-table; layer 2: agg
// over 8 MB fp8 e4m3 hB' table (R14/R15: gather pinned ~43 us by per-edge
// line-request service — invariant to table size/ILP/order; optimize around it).
// h1 exists only in LDS (fused w1+w2). Pads -> dedicated zero row N_NODES.

#define N_NODES 131072
#define N_EDGES 2097152
#define N_GRAPHS 2048
#define IN_CH 12
#define HID 64
#define OUT_CH 4
#define NBUCK 512          // buckets of 256 dst nodes
#define CHUNK 8192         // edges per bucket_kernel block
#define STRIDE 4608        // staging capacity per bucket (mean 4096, sd 64)
#define CSR_STRIDE 5120    // csr capacity per bucket (padded mean ~4500)
#define CAP 5120           // build_kernel LDS image capacity (20.5 KB, int)

typedef float f32x2 __attribute__((ext_vector_type(2)));

__device__ __forceinline__ unsigned short f2bf(float f) {
    unsigned u = __float_as_uint(f);
    return (unsigned short)((u + 0x7fffu + ((u >> 16) & 1u)) >> 16);  // RNE
}
__device__ __forceinline__ unsigned pack2bf(float lo, float hi) {
    return (unsigned)f2bf(lo) | ((unsigned)f2bf(hi) << 16);
}
__device__ __forceinline__ float bflo(unsigned v) { return __uint_as_float(v << 16); }
__device__ __forceinline__ float bfhi(unsigned v) { return __uint_as_float(v & 0xFFFF0000u); }

// ---- pass A: LDS bucket sort of edges by dst>>8 into strided staging ----
__global__ __launch_bounds__(1024, 4)
void bucket_kernel(const int* __restrict__ src, const int* __restrict__ dst,
                   int* __restrict__ bucket_count, int* __restrict__ staged) {
    __shared__ int hist[NBUCK];
    __shared__ int lscan[NBUCK];
    __shared__ int gbase[NBUCK];
    __shared__ int cursor[NBUCK];
    __shared__ int sorted[CHUNK];  // 32 KB
    int tid = threadIdx.x;
    int base = blockIdx.x * CHUNK;
    if (tid < NBUCK) { hist[tid] = 0; cursor[tid] = 0; }
    __syncthreads();
    int d8[8], s8[8];
#pragma unroll
    for (int k = 0; k < 8; k++) {
        int i = base + k * 1024 + tid;
        d8[k] = dst[i];
        s8[k] = src[i];
        atomicAdd(&hist[d8[k] >> 8], 1);
    }
    __syncthreads();
    if (tid < NBUCK) lscan[tid] = hist[tid];
    __syncthreads();
    for (int off = 1; off < NBUCK; off <<= 1) {
        int u = (tid < NBUCK && tid >= off) ? lscan[tid - off] : 0;
        __syncthreads();
        if (tid < NBUCK) lscan[tid] += u;
        __syncthreads();
    }
    if (tid < NBUCK) gbase[tid] = atomicAdd(&bucket_count[tid], hist[tid]);
    __syncthreads();
#pragma unroll
    for (int k = 0; k < 8; k++) {
        int b = d8[k] >> 8;
        int start = lscan[b] - hist[b];
        int p = start + atomicAdd(&cursor[b], 1);
        sorted[p] = ((d8[k] & 255) << 17) | s8[k];
    }
    __syncthreads();
    int wid = tid >> 6, lane = tid & 63;
    int g16 = lane >> 4, k16 = lane & 15;
    for (int b0 = wid * 4; b0 < NBUCK; b0 += 64) {
        int b = b0 + g16;
        int cb = hist[b];
        int lbase = lscan[b] - cb;
        int gb = b * STRIDE + gbase[b];
        for (int k = k16; k < cb; k += 16) staged[gb + k] = sorted[lbase + k];
    }
}

// ---- per-bucket: count + scan + place, all in one kernel (slice in LDS) ----
// Also writes dinv, rowbounds, and the dinv-prescaled bf16 x-table row.
__global__ void build_kernel(const int* __restrict__ bucket_count, const int* __restrict__ staged,
                             int2* __restrict__ rowbounds, float* __restrict__ dinv,
                             int* __restrict__ csr, const float* __restrict__ x,
                             unsigned short* __restrict__ xb) {
    __shared__ int sl[STRIDE];     // 18.4 KB bucket slice
    __shared__ int image[CAP];     // 20.5 KB csr image (src<<6)
    __shared__ int cnt[256];
    __shared__ int scn[256];
    __shared__ int loff[256];
    __shared__ int cursor[256];
    __shared__ int totalS;
    int b = blockIdx.x;
    int tid = threadIdx.x;
    int count = bucket_count[b];
    const int* st = staged + b * STRIDE;
    cnt[tid] = 0;
    cursor[tid] = 0;
    for (int i = tid; i < count; i += 256) sl[i] = st[i];
    __syncthreads();
    for (int i = tid; i < count; i += 256) atomicAdd(&cnt[(sl[i] >> 17) & 255], 1);
    __syncthreads();
    int deg = cnt[tid];
    int degp = (deg + 3) & ~3;  // pad to x4
    scn[tid] = degp;
    __syncthreads();
    for (int off = 1; off < 256; off <<= 1) {
        int u = (tid >= off) ? scn[tid - off] : 0;
        __syncthreads();
        scn[tid] += u;
        __syncthreads();
    }
    int lo = scn[tid] - degp;
    loff[tid] = lo;
    int nbase = (b << 8) + tid;
    int gb = b * CSR_STRIDE;
    rowbounds[nbase] = make_int2(gb + lo, gb + lo + degp);
    float dv = rsqrtf((float)deg + 1.0f);
    dinv[nbase] = dv;
    if (tid == 255) totalS = lo + degp;
    // prescaled x cast: xb'[n] = dinv[n] * x[n] (bf16, 16-ch padded)
    {
        const float* xp = x + nbase * IN_CH;
        unsigned o[8];
#pragma unroll
        for (int k = 0; k < 6; k++) o[k] = pack2bf(dv * xp[2 * k], dv * xp[2 * k + 1]);
        o[6] = 0; o[7] = 0;
        uint4* dstp = (uint4*)(xb + nbase * 16);
        dstp[0] = make_uint4(o[0], o[1], o[2], o[3]);
        dstp[1] = make_uint4(o[4], o[5], o[6], o[7]);
    }
    if (b == 0 && tid < 2)  // zero row N_NODES of xb (pad target)
        ((uint4*)(xb + (size_t)N_NODES * 16))[tid] = make_uint4(0, 0, 0, 0);
    __syncthreads();
    // place
    for (int i = tid; i < count; i += 256) {
        int rec = sl[i];
        int s = rec & 0x1FFFF;
        int dq = (rec >> 17) & 255;
        int p = loff[dq] + atomicAdd(&cursor[dq], 1);
        int val = s << 6;  // byte offset (fp8) / x16 row via >>2 (bf16 x)
        if (p < CAP) image[p] = val;
        else csr[gb + p] = val;  // statistical-tail fallback
    }
    __syncthreads();
    int padval = N_NODES << 6;  // zero row
    for (int p = loff[tid] + deg; p < loff[tid] + degp; p++) {
        if (p < CAP) image[p] = padval;
        else csr[gb + p] = padval;
    }
    __syncthreads();
    int lim = totalS < CAP ? totalS : CAP;
    int* dstp = csr + gb;
    for (int i = tid; i < lim; i += 256) dstp[i] = image[i];
}

// ---- layer-1 aggregation over prescaled x table: wave = 32 nodes ----
__global__ void agg_x_kernel(const int2* __restrict__ rowbounds, const int* __restrict__ csr,
                             const float* __restrict__ dinv,
                             const unsigned short* __restrict__ xb, float* __restrict__ aggx) {
    int tid = threadIdx.x;
    int w = tid >> 6, lane = tid & 63, sub = lane >> 1, p = lane & 1;
    int qoff = 8 * p;
    int node = (blockIdx.x * 4 + w) * 32 + sub;
    int2 rb = rowbounds[node];
    float dn = dinv[node];
    f32x2 a0[4] = {{0, 0}, {0, 0}, {0, 0}, {0, 0}};
    f32x2 a1[4] = {{0, 0}, {0, 0}, {0, 0}, {0, 0}};
    f32x2 a2[4] = {{0, 0}, {0, 0}, {0, 0}, {0, 0}};
    f32x2 a3[4] = {{0, 0}, {0, 0}, {0, 0}, {0, 0}};
    for (int j = rb.x; j < rb.y; j += 4) {  // padded x4: no remainder
        int4 e = *(const int4*)(csr + j);
        uint4 u0 = *(const uint4*)(xb + (e.x >> 2) + qoff);
        uint4 u1 = *(const uint4*)(xb + (e.y >> 2) + qoff);
        uint4 u2 = *(const uint4*)(xb + (e.z >> 2) + qoff);
        uint4 u3 = *(const uint4*)(xb + (e.w >> 2) + qoff);
        a0[0] += (f32x2){bflo(u0.x), bfhi(u0.x)};
        a0[1] += (f32x2){bflo(u0.y), bfhi(u0.y)};
        a0[2] += (f32x2){bflo(u0.z), bfhi(u0.z)};
        a0[3] += (f32x2){bflo(u0.w), bfhi(u0.w)};
        a1[0] += (f32x2){bflo(u1.x), bfhi(u1.x)};
        a1[1] += (f32x2){bflo(u1.y), bfhi(u1.y)};
        a1[2] += (f32x2){bflo(u1.z), bfhi(u1.z)};
        a1[3] += (f32x2){bflo(u1.w), bfhi(u1.w)};
        a2[0] += (f32x2){bflo(u2.x), bfhi(u2.x)};
        a2[1] += (f32x2){bflo(u2.y), bfhi(u2.y)};
        a2[2] += (f32x2){bflo(u2.z), bfhi(u2.z)};
        a2[3] += (f32x2){bflo(u2.w), bfhi(u2.w)};
        a3[0] += (f32x2){bflo(u3.x), bfhi(u3.x)};
        a3[1] += (f32x2){bflo(u3.y), bfhi(u3.y)};
        a3[2] += (f32x2){bflo(u3.z), bfhi(u3.z)};
        a3[3] += (f32x2){bflo(u3.w), bfhi(u3.w)};
    }
    uint4 su = *(const uint4*)(xb + node * 16 + qoff);  // xb' already has dinv_s
    a0[0] += (f32x2){bflo(su.x), bfhi(su.x)};
    a0[1] += (f32x2){bflo(su.y), bfhi(su.y)};
    a0[2] += (f32x2){bflo(su.z), bfhi(su.z)};
    a0[3] += (f32x2){bflo(su.w), bfhi(su.w)};
    f32x2 nd = {dn, dn};
    f32x2 s0 = nd * ((a0[0] + a1[0]) + (a2[0] + a3[0]));
    f32x2 s1 = nd * ((a0[1] + a1[1]) + (a2[1] + a3[1]));
    f32x2 s2 = nd * ((a0[2] + a1[2]) + (a2[2] + a3[2]));
    f32x2 s3 = nd * ((a0[3] + a1[3]) + (a2[3] + a3[3]));
    float4 o0 = make_float4(s0[0], s0[1], s1[0], s1[1]);
    float4 o1 = make_float4(s2[0], s2[1], s3[0], s3[1]);
    *(float4*)(aggx + node * 16 + qoff) = o0;       // 64 B row = 1 full line
    *(float4*)(aggx + node * 16 + qoff + 4) = o1;
}

// ---- fused: h1 = relu(aggx@W1+b1) in LDS; hB' = dinv * (h1@W2) -> fp8 ----
__global__ void w1w2_kernel(const float* __restrict__ aggx, const float* __restrict__ W1,
                            const float* __restrict__ b1, const float* __restrict__ W2,
                            const float* __restrict__ dinv, unsigned int* __restrict__ hout) {
    __shared__ float sW1[IN_CH * HID];   // 3 KB
    __shared__ float sW2[HID * HID];     // 16 KB
    __shared__ float sA[256];            // 16 nodes x 16
    __shared__ float sh1[16 * HID];      // 4 KB
    int tid = threadIdx.x;
    for (int i = tid; i < IN_CH * HID; i += 256) sW1[i] = W1[i];
    for (int i = tid; i < HID * HID; i += 256) sW2[i] = W2[i];
    int node0 = blockIdx.x * 16;
    sA[tid] = aggx[node0 * 16 + tid];
    __syncthreads();
    int nl = tid >> 4, c4 = (tid & 15) * 4;
    float a0 = 0, a1 = 0, a2 = 0, a3 = 0;
#pragma unroll
    for (int k = 0; k < IN_CH; k++) {
        float av = sA[nl * 16 + k];
        const float* w = &sW1[k * HID + c4];
        a0 += av * w[0]; a1 += av * w[1]; a2 += av * w[2]; a3 += av * w[3];
    }
    const float* bb = &b1[c4];
    sh1[nl * HID + c4 + 0] = fmaxf(a0 + bb[0], 0.0f);
    sh1[nl * HID + c4 + 1] = fmaxf(a1 + bb[1], 0.0f);
    sh1[nl * HID + c4 + 2] = fmaxf(a2 + bb[2], 0.0f);
    sh1[nl * HID + c4 + 3] = fmaxf(a3 + bb[3], 0.0f);
    __syncthreads();
    float c0 = 0, c1 = 0, c2 = 0, c3 = 0;
#pragma unroll 8
    for (int k = 0; k < HID; k++) {
        float hv = sh1[nl * HID + k];
        float4 w = *(const float4*)&sW2[k * HID + c4];
        c0 += hv * w.x; c1 += hv * w.y; c2 += hv * w.z; c3 += hv * w.w;
    }
    float dv = dinv[node0 + nl];
    unsigned int packed = (unsigned int)__builtin_amdgcn_cvt_pk_fp8_f32(dv * c0, dv * c1, 0, false);
    packed = (unsigned int)__builtin_amdgcn_cvt_pk_fp8_f32(dv * c2, dv * c3, (int)packed, true);
    hout[((node0 + nl) * HID + c4) >> 2] = packed;  // 4 B/thread, coalesced
    if (blockIdx.x == 0 && tid < 16)  // zero row N_NODES of hB (pad target)
        hout[((size_t)N_NODES * HID >> 2) + tid] = 0;
}

// ---- layer-2 fp8 gather body: no per-edge norm; 8 edges in flight ----
__device__ __forceinline__ void add_fp8(f32x2* a, uint2 u) {
    a[0] += __builtin_amdgcn_cvt_pk_f32_fp8((int)u.x, false);
    a[1] += __builtin_amdgcn_cvt_pk_f32_fp8((int)u.x, true);
    a[2] += __builtin_amdgcn_cvt_pk_f32_fp8((int)u.y, false);
    a[3] += __builtin_amdgcn_cvt_pk_f32_fp8((int)u.y, true);
}

__device__ __forceinline__ void agg_body(int beg, int end, const int* __restrict__ csr,
                                         const unsigned char* __restrict__ h,
                                         int qoff, float* r) {
    f32x2 a0[4] = {{0, 0}, {0, 0}, {0, 0}, {0, 0}};
    f32x2 a1[4] = {{0, 0}, {0, 0}, {0, 0}, {0, 0}};
    f32x2 a2[4] = {{0, 0}, {0, 0}, {0, 0}, {0, 0}};
    f32x2 a3[4] = {{0, 0}, {0, 0}, {0, 0}, {0, 0}};
    int j = beg;
    for (; j + 8 <= end; j += 8) {  // 8 edges in flight
        int4 ea = *(const int4*)(csr + j);
        int4 eb = *(const int4*)(csr + j + 4);
        uint2 u0 = *(const uint2*)(h + ea.x + qoff);
        uint2 u1 = *(const uint2*)(h + ea.y + qoff);
        uint2 u2 = *(const uint2*)(h + ea.z + qoff);
        uint2 u3 = *(const uint2*)(h + ea.w + qoff);
        uint2 u4 = *(const uint2*)(h + eb.x + qoff);
        uint2 u5 = *(const uint2*)(h + eb.y + qoff);
        uint2 u6 = *(const uint2*)(h + eb.z + qoff);
        uint2 u7 = *(const uint2*)(h + eb.w + qoff);
        add_fp8(a0, u0); add_fp8(a1, u1); add_fp8(a2, u2); add_fp8(a3, u3);
        add_fp8(a0, u4); add_fp8(a1, u5); add_fp8(a2, u6); add_fp8(a3, u7);
    }
    if (j < end) {  // exactly 4 padded edges remain
        int4 ea = *(const int4*)(csr + j);
        uint2 u0 = *(const uint2*)(h + ea.x + qoff);
        uint2 u1 = *(const uint2*)(h + ea.y + qoff);
        uint2 u2 = *(const uint2*)(h + ea.z + qoff);
        uint2 u3 = *(const uint2*)(h + ea.w + qoff);
        add_fp8(a0, u0); add_fp8(a1, u1); add_fp8(a2, u2); add_fp8(a3, u3);
    }
#pragma unroll
    for (int k = 0; k < 4; k++) {
        f32x2 s = (a0[k] + a1[k]) + (a2[k] + a3[k]);
        r[2 * k] = s[0];
        r[2 * k + 1] = s[1];
    }
}

// ---- layer-2 gather-aggregate + relu + fused mean-pool (run-length flush) ----
__global__ void agg_pool_kernel(const int2* __restrict__ rowbounds, const int* __restrict__ csr,
                                const float* __restrict__ dinv,
                                const unsigned char* __restrict__ h,
                                const float* __restrict__ b, const int* __restrict__ batch,
                                float* __restrict__ pool, float* __restrict__ gcnt) {
    __shared__ float red[32][HID];  // 8 KB
    __shared__ int gids[32];
    int tid = threadIdx.x;
    int w = tid >> 6, lane = tid & 63, sub = lane >> 3, q = lane & 7;
    int qoff = 8 * q;
    int node = (blockIdx.x * 4 + w) * 8 + sub;
    int2 rb = rowbounds[node];
    float dn = dinv[node];
    float r[8];
    agg_body(rb.x, rb.y, csr, h, qoff, r);
    uint2 su = *(const uint2*)(h + node * HID + qoff);  // hB' already has dinv_s
    f32x2 s0 = __builtin_amdgcn_cvt_pk_f32_fp8((int)su.x, false);
    f32x2 s1 = __builtin_amdgcn_cvt_pk_f32_fp8((int)su.x, true);
    f32x2 s2 = __builtin_amdgcn_cvt_pk_f32_fp8((int)su.y, false);
    f32x2 s3 = __builtin_amdgcn_cvt_pk_f32_fp8((int)su.y, true);
    float4 b0 = *(const float4*)&b[qoff];
    float4 b1 = *(const float4*)&b[qoff + 4];
    float4 v0, v1;
    v0.x = fmaxf(dn * (r[0] + s0[0]) + b0.x, 0.0f);
    v0.y = fmaxf(dn * (r[1] + s0[1]) + b0.y, 0.0f);
    v0.z = fmaxf(dn * (r[2] + s1[0]) + b0.z, 0.0f);
    v0.w = fmaxf(dn * (r[3] + s1[1]) + b0.w, 0.0f);
    v1.x = fmaxf(dn * (r[4] + s2[0]) + b1.x, 0.0f);
    v1.y = fmaxf(dn * (r[5] + s2[1]) + b1.y, 0.0f);
    v1.z = fmaxf(dn * (r[6] + s3[0]) + b1.z, 0.0f);
    v1.w = fmaxf(dn * (r[7] + s3[1]) + b1.w, 0.0f);
    int nl = w * 8 + sub;
    *(float4*)&red[nl][qoff] = v0;
    *(float4*)&red[nl][qoff + 4] = v1;
    if (q == 0) gids[nl] = batch[node];
    __syncthreads();
    if (tid < 64) {  // wave 0: run-length reduce 32 nodes (batch sorted)
        int c = tid;
        float acc = 0.0f;
        int cur = gids[0], cnt = 0;
        for (int n = 0; n < 32; n++) {
            int g = gids[n];
            if (g != cur) {
                atomicAdd(&pool[cur * HID + c], acc);
                if (c == 0) atomicAdd(&gcnt[cur], (float)cnt);
                acc = 0.0f; cnt = 0; cur = g;
            }
            acc += red[n][c];
            cnt++;
        }
        atomicAdd(&pool[cur * HID + c], acc);
        if (c == 0) atomicAdd(&gcnt[cur], (float)cnt);
    }
}

// ---- final: out = sigmoid((pool/cnt) @ Wfc + bfc) ----
__global__ void final_kernel(const float* __restrict__ pool, const float* __restrict__ gcnt,
                             const float* __restrict__ Wfc, const float* __restrict__ bfc,
                             float* __restrict__ out) {
    int idx = blockIdx.x * 256 + threadIdx.x;
    if (idx >= N_GRAPHS * OUT_CH) return;
    int g = idx >> 2, o = idx & 3;
    float inv = 1.0f / fmaxf(gcnt[g], 1.0f);
    float acc = bfc[o];
#pragma unroll
    for (int k = 0; k < HID; k++) acc += pool[g * HID + k] * inv * Wfc[k * OUT_CH + o];
    out[idx] = 1.0f / (1.0f + expf(-acc));
}

extern "C" void kernel_launch(void* const* d_in, const int* in_sizes, int n_in,
                              void* d_out, int out_size, void* d_ws, size_t ws_size,
                              hipStream_t stream) {
    const float* x   = (const float*)d_in[0];
    const int* eidx  = (const int*)d_in[1];
    const int* batch = (const int*)d_in[2];
    const float* W1  = (const float*)d_in[3];
    const float* b1  = (const float*)d_in[4];
    const float* W2  = (const float*)d_in[5];
    const float* b2  = (const float*)d_in[6];
    const float* Wfc = (const float*)d_in[7];
    const float* bfc = (const float*)d_in[8];
    float* out = (float*)d_out;

    const int* src = eidx;
    const int* dst = eidx + N_EDGES;

    // workspace layout (~45 MB)
    unsigned char* hB = (unsigned char*)d_ws;                 // 8 MB fp8 (+1 zero row)
    int*   csr    = (int*)(hB + (size_t)(N_NODES + 1) * HID); // 10.5 MB src<<6
    int*   staged = csr + (size_t)NBUCK * CSR_STRIDE;         // 9.4 MB bucket-strided
    float* dinv   = (float*)(staged + (size_t)NBUCK * STRIDE); // 512 KB
    int2*  rowbounds = (int2*)(dinv + N_NODES);               // 1 MB
    int*   bucket_count = (int*)(rowbounds + N_NODES);        // 2 KB
    float* pool   = (float*)(bucket_count + NBUCK);           // 512 KB
    float* gcnt   = pool + N_GRAPHS * HID;                    // 8 KB
    unsigned short* xb = (unsigned short*)(gcnt + N_GRAPHS);  // 4 MB bf16 [N+1,16]
    float* aggx   = (float*)(xb + (size_t)(N_NODES + 1) * 16); // 8 MB fp32 [N,16]

    hipMemsetAsync(bucket_count, 0, (size_t)NBUCK * 4, stream);
    hipMemsetAsync(pool, 0, (size_t)(N_GRAPHS * HID + N_GRAPHS) * 4, stream);

    // CSR build: bucket sort -> fused count/scan/place (+prescaled xcast)
    bucket_kernel<<<N_EDGES / CHUNK, 1024, 0, stream>>>(src, dst, bucket_count, staged);
    build_kernel<<<NBUCK, 256, 0, stream>>>(bucket_count, staged, rowbounds, dinv, csr, x, xb);

    // layer 1: agg(x') then fused W1+W2 (h1 LDS-only) -> fp8 hB'
    agg_x_kernel<<<N_NODES / 128, 256, 0, stream>>>(rowbounds, csr, dinv, xb, aggx);
    w1w2_kernel<<<N_NODES / 16, 256, 0, stream>>>(aggx, W1, b1, W2, dinv, (unsigned int*)hB);

    // layer 2: gather + pool
    agg_pool_kernel<<<N_NODES / 32, 256, 0, stream>>>(rowbounds, csr, dinv, hB, b2, batch,
                                                      pool, gcnt);

    // head
    final_kernel<<<(N_GRAPHS * OUT_CH + 255) / 256, 256, 0, stream>>>(pool, gcnt, Wfc, bfc, out);
}